// Round 1
// baseline (4703.127 us; speedup 1.0000x reference)
//
#include <hip/hip_runtime.h>
#include <math.h>

#define HDIM 128

// ---------------- setup kernels ----------------

__global__ void deg_kernel(const int* __restrict__ src, float* __restrict__ deg, int E) {
    int e = blockIdx.x * blockDim.x + threadIdx.x;
    if (e < E) atomicAdd(&deg[src[e]], 1.0f);
}

__global__ void dinv_kernel(float* deg, int N) {
    int i = blockIdx.x * blockDim.x + threadIdx.x;
    if (i < N) { float d = deg[i]; deg[i] = d > 0.f ? rsqrtf(d) : 0.f; }
}

__global__ void ew_kernel(const int* __restrict__ src, const int* __restrict__ dst,
                          const float* __restrict__ dinv, float* __restrict__ w, int E) {
    int e = blockIdx.x * blockDim.x + threadIdx.x;
    if (e < E) w[e] = -dinv[src[e]] * dinv[dst[e]];
}

// ---------------- propagation (push, atomic) ----------------
// out[dst,:] += alpha * w[e] * t[src,:]   (H=128, 2 edges per 256-thr block)
__global__ void prop128_kernel(const float* __restrict__ t, const float* __restrict__ w,
                               const int* __restrict__ src, const int* __restrict__ dst,
                               float* __restrict__ out, float alpha, int E) {
    int e = blockIdx.x * 2 + (threadIdx.x >> 7);
    if (e >= E) return;
    int c = threadIdx.x & 127;
    int s = src[e], d = dst[e];
    float v = alpha * w[e] * t[(size_t)s * HDIM + c];
    atomicAdd(&out[(size_t)d * HDIM + c], v);
}

__global__ void prop3_kernel(const float* __restrict__ t, const float* __restrict__ w,
                             const int* __restrict__ src, const int* __restrict__ dst,
                             float* __restrict__ out, float alpha, int E) {
    int e = blockIdx.x * blockDim.x + threadIdx.x;
    if (e >= E) return;
    int s = src[e], d = dst[e];
    float we = alpha * w[e];
    atomicAdd(&out[d * 3 + 0], we * t[s * 3 + 0]);
    atomicAdd(&out[d * 3 + 1], we * t[s * 3 + 1]);
    atomicAdd(&out[d * 3 + 2], we * t[s * 3 + 2]);
}

__global__ void neg_kernel(const float* __restrict__ in, float* __restrict__ out, int n) {
    int i = blockIdx.x * blockDim.x + threadIdx.x;
    if (i < n) out[i] = -in[i];
}

// ---------------- fused Cheb GEMM: Z = sum_k T_k @ W_k + b, act, BN-stats ----------------
// ACT: 0 none, 1 leaky(0.01), 2 relu.  STATS: accumulate per-column sum/sumsq.
template <int ACT, int STATS>
__global__ __launch_bounds__(256)
void gemm_cheb(const float* __restrict__ T0, const float* __restrict__ T1,
               const float* __restrict__ T2, const float* __restrict__ T3,
               const float* __restrict__ W, const float* __restrict__ bias,
               float* __restrict__ out, float* __restrict__ stats, int N) {
    __shared__ float As[8][128];
    __shared__ float Bs[8][128];
    __shared__ float s_sum[128];
    __shared__ float s_sq[128];
    int tid = threadIdx.x;
    int tx = tid & 15, ty = tid >> 4;
    int row0 = blockIdx.x * 128;
    float acc[8][8] = {};
    const float* Ts[4] = {T0, T1, T2, T3};
    if (STATS && tid < 128) { s_sum[tid] = 0.f; s_sq[tid] = 0.f; }

    int ar = tid >> 1;            // A row 0..127
    int ac = (tid & 1) * 4;       // A col offset 0 or 4
    int br = tid >> 5;            // B row 0..7
    int bc = (tid * 4) & 127;     // B col

    for (int sel = 0; sel < 4; ++sel) {
        const float* __restrict__ Tp = Ts[sel];
        const float* __restrict__ Wp = W + sel * 128 * 128;
        for (int kt = 0; kt < 16; ++kt) {
            int k0 = kt * 8;
            __syncthreads();
            float4 av = make_float4(0.f, 0.f, 0.f, 0.f);
            if (row0 + ar < N)
                av = *(const float4*)(Tp + (size_t)(row0 + ar) * 128 + k0 + ac);
            As[ac + 0][ar] = av.x; As[ac + 1][ar] = av.y;
            As[ac + 2][ar] = av.z; As[ac + 3][ar] = av.w;
            float4 bv = *(const float4*)(Wp + (size_t)(k0 + br) * 128 + bc);
            *(float4*)(&Bs[br][bc]) = bv;
            __syncthreads();
#pragma unroll
            for (int kk = 0; kk < 8; ++kk) {
                float a[8], b[8];
#pragma unroll
                for (int i = 0; i < 8; ++i) a[i] = As[kk][ty * 8 + i];
#pragma unroll
                for (int j = 0; j < 8; ++j) b[j] = Bs[kk][tx * 8 + j];
#pragma unroll
                for (int i = 0; i < 8; ++i)
#pragma unroll
                    for (int j = 0; j < 8; ++j) acc[i][j] += a[i] * b[j];
            }
        }
    }

    float csum[8] = {}, csq[8] = {};
#pragma unroll
    for (int i = 0; i < 8; ++i) {
        int r = row0 + ty * 8 + i;
        if (r < N) {
#pragma unroll
            for (int j = 0; j < 8; ++j) {
                int c = tx * 8 + j;
                float v = acc[i][j] + bias[c];
                if (ACT == 1) v = v >= 0.f ? v : 0.01f * v;
                else if (ACT == 2) v = fmaxf(v, 0.f);
                out[(size_t)r * 128 + c] = v;
                if (STATS) { csum[j] += v; csq[j] += v * v; }
            }
        }
    }
    if (STATS) {
#pragma unroll
        for (int j = 0; j < 8; ++j) {
            atomicAdd(&s_sum[tx * 8 + j], csum[j]);
            atomicAdd(&s_sq[tx * 8 + j], csq[j]);
        }
        __syncthreads();
        if (tid < 128) {
            atomicAdd(&stats[tid], s_sum[tid]);
            atomicAdd(&stats[128 + tid], s_sq[tid]);
        }
    }
}

// ---------------- layer-1 (input dim 3) fused GEMM ----------------
__global__ __launch_bounds__(256)
void gemm1_kernel(const float* __restrict__ x, const float* __restrict__ t1,
                  const float* __restrict__ t2, const float* __restrict__ t3,
                  const float* __restrict__ W1, const float* __restrict__ b1,
                  float* __restrict__ out, float* __restrict__ stats, int N) {
    __shared__ float s_sum[128];
    __shared__ float s_sq[128];
    int tid = threadIdx.x;
    int c = tid & 127;
    int row = blockIdx.x * 2 + (tid >> 7);
    if (tid < 128) { s_sum[tid] = 0.f; s_sq[tid] = 0.f; }
    __syncthreads();
    if (row < N) {
        float v = b1[c];
        const float* Ts[4] = {x, t1, t2, t3};
#pragma unroll
        for (int k = 0; k < 4; ++k) {
            const float* t = Ts[k];
#pragma unroll
            for (int d = 0; d < 3; ++d)
                v += t[row * 3 + d] * W1[(k * 3 + d) * 128 + c];
        }
        v = v >= 0.f ? v : 0.01f * v;   // leaky_relu
        out[(size_t)row * 128 + c] = v;
        atomicAdd(&s_sum[c], v);
        atomicAdd(&s_sq[c], v * v);
    }
    __syncthreads();
    if (tid < 128) {
        atomicAdd(&stats[tid], s_sum[tid]);
        atomicAdd(&stats[128 + tid], s_sq[tid]);
    }
}

// ---------------- BN finalize + apply ----------------
__global__ void bnfin_kernel(const float* __restrict__ stats, const float* __restrict__ g,
                             const float* __restrict__ be, float* __restrict__ bnp, float invN) {
    int c = threadIdx.x;  // 128 threads
    float m = stats[c] * invN;
    float v = stats[128 + c] * invN - m * m;
    float sc = g[c] * rsqrtf(v + 1e-5f);
    bnp[c] = sc;
    bnp[128 + c] = be[c] - m * sc;
}

__global__ void bnapply_kernel(const float* __restrict__ z, const float* __restrict__ bnp,
                               float* __restrict__ outp, int n) {
    int i = blockIdx.x * blockDim.x + threadIdx.x;
    if (i < n) {
        int c = i & 127;
        outp[i] = z[i] * bnp[c] + bnp[128 + c];
    }
}

// ---------------- final: L2-normalize row + project to 3 ----------------
__global__ void final_kernel(const float* __restrict__ Z, const float* __restrict__ Wm,
                             const float* __restrict__ bm, float* __restrict__ out, int N) {
    int gid = blockIdx.x * blockDim.x + threadIdx.x;
    int node = gid >> 6;
    int lane = threadIdx.x & 63;
    if (node >= N) return;
    const float* z = Z + (size_t)node * 128;
    float z0 = z[lane], z1 = z[lane + 64];
    float sq = z0 * z0 + z1 * z1;
    float d0 = z0 * Wm[lane * 3 + 0] + z1 * Wm[(lane + 64) * 3 + 0];
    float d1 = z0 * Wm[lane * 3 + 1] + z1 * Wm[(lane + 64) * 3 + 1];
    float d2 = z0 * Wm[lane * 3 + 2] + z1 * Wm[(lane + 64) * 3 + 2];
#pragma unroll
    for (int off = 32; off > 0; off >>= 1) {
        sq += __shfl_down(sq, off);
        d0 += __shfl_down(d0, off);
        d1 += __shfl_down(d1, off);
        d2 += __shfl_down(d2, off);
    }
    if (lane == 0) {
        float inv = 1.f / fmaxf(sqrtf(sq), 1e-12f);
        out[node * 3 + 0] = d0 * inv + bm[0];
        out[node * 3 + 1] = d1 * inv + bm[1];
        out[node * 3 + 2] = d2 * inv + bm[2];
    }
}

// ---------------- host ----------------

extern "C" void kernel_launch(void* const* d_in, const int* in_sizes, int n_in,
                              void* d_out, int out_size, void* d_ws, size_t ws_size,
                              hipStream_t stream) {
    const float* x  = (const float*)d_in[0];
    const int*   ei = (const int*)d_in[1];
    const float* W1 = (const float*)d_in[2];
    const float* b1 = (const float*)d_in[3];
    const float* W2 = (const float*)d_in[4];
    const float* b2 = (const float*)d_in[5];
    const float* W3 = (const float*)d_in[6];
    const float* b3 = (const float*)d_in[7];
    const float* W4 = (const float*)d_in[8];
    const float* b4 = (const float*)d_in[9];
    const float* g1 = (const float*)d_in[10];
    const float* be1 = (const float*)d_in[11];
    const float* g2 = (const float*)d_in[12];
    const float* be2 = (const float*)d_in[13];
    const float* g3 = (const float*)d_in[14];
    const float* be3 = (const float*)d_in[15];
    const float* Wm = (const float*)d_in[16];
    const float* bm = (const float*)d_in[17];
    float* out = (float*)d_out;

    const int N = in_sizes[0] / 3;
    const int E = in_sizes[1] / 2;
    const size_t NH = (size_t)N * HDIM;
    const int* src = ei;
    const int* dst = ei + E;

    float* p = (float*)d_ws;
    float* dinv = p; p += N;
    float* w    = p; p += E;
    float* A    = p; p += NH;   // current layer input / Tx0
    float* T1   = p; p += NH;
    float* T2   = p; p += NH;
    float* T3   = p; p += NH;
    float* Z    = p; p += NH;   // GEMM output
    float* x1   = p; p += (size_t)N * 3;
    float* x2   = p; p += (size_t)N * 3;
    float* x3   = p; p += (size_t)N * 3;
    float* stats = p; p += 256;
    float* bnp   = p; p += 256;

    const int EB = (E + 255) / 256;
    const int NB = (N + 255) / 256;
    const int GB = (N + 127) / 128;       // gemm row tiles
    const int PB = (E + 1) / 2;           // prop128 blocks
    const int NHB = (int)((NH + 255) / 256);

    // --- edge normalization ---
    hipMemsetAsync(dinv, 0, (size_t)N * 4, stream);
    deg_kernel<<<EB, 256, 0, stream>>>(src, dinv, E);
    dinv_kernel<<<NB, 256, 0, stream>>>(dinv, N);
    ew_kernel<<<EB, 256, 0, stream>>>(src, dst, dinv, w, E);

    // --- layer 1 (dim 3) ---
    hipMemsetAsync(x1, 0, (size_t)N * 3 * 4, stream);
    prop3_kernel<<<EB, 256, 0, stream>>>(x, w, src, dst, x1, 1.f, E);
    neg_kernel<<<(N * 3 + 255) / 256, 256, 0, stream>>>(x, x2, N * 3);
    prop3_kernel<<<EB, 256, 0, stream>>>(x1, w, src, dst, x2, 2.f, E);
    neg_kernel<<<(N * 3 + 255) / 256, 256, 0, stream>>>(x1, x3, N * 3);
    prop3_kernel<<<EB, 256, 0, stream>>>(x2, w, src, dst, x3, 2.f, E);
    hipMemsetAsync(stats, 0, 256 * 4, stream);
    gemm1_kernel<<<(N + 1) / 2, 256, 0, stream>>>(x, x1, x2, x3, W1, b1, Z, stats, N);
    bnfin_kernel<<<1, 128, 0, stream>>>(stats, g1, be1, bnp, 1.f / (float)N);
    bnapply_kernel<<<NHB, 256, 0, stream>>>(Z, bnp, A, (int)NH);

    // --- layer 2 (leaky + BN) ---
    hipMemsetAsync(T1, 0, NH * 4, stream);
    prop128_kernel<<<PB, 256, 0, stream>>>(A, w, src, dst, T1, 1.f, E);
    neg_kernel<<<NHB, 256, 0, stream>>>(A, T2, (int)NH);
    prop128_kernel<<<PB, 256, 0, stream>>>(T1, w, src, dst, T2, 2.f, E);
    neg_kernel<<<NHB, 256, 0, stream>>>(T1, T3, (int)NH);
    prop128_kernel<<<PB, 256, 0, stream>>>(T2, w, src, dst, T3, 2.f, E);
    hipMemsetAsync(stats, 0, 256 * 4, stream);
    gemm_cheb<1, 1><<<GB, 256, 0, stream>>>(A, T1, T2, T3, W2, b2, Z, stats, N);
    bnfin_kernel<<<1, 128, 0, stream>>>(stats, g2, be2, bnp, 1.f / (float)N);
    bnapply_kernel<<<NHB, 256, 0, stream>>>(Z, bnp, A, (int)NH);

    // --- layer 3 (relu + BN) ---
    hipMemsetAsync(T1, 0, NH * 4, stream);
    prop128_kernel<<<PB, 256, 0, stream>>>(A, w, src, dst, T1, 1.f, E);
    neg_kernel<<<NHB, 256, 0, stream>>>(A, T2, (int)NH);
    prop128_kernel<<<PB, 256, 0, stream>>>(T1, w, src, dst, T2, 2.f, E);
    neg_kernel<<<NHB, 256, 0, stream>>>(T1, T3, (int)NH);
    prop128_kernel<<<PB, 256, 0, stream>>>(T2, w, src, dst, T3, 2.f, E);
    hipMemsetAsync(stats, 0, 256 * 4, stream);
    gemm_cheb<2, 1><<<GB, 256, 0, stream>>>(A, T1, T2, T3, W3, b3, Z, stats, N);
    bnfin_kernel<<<1, 128, 0, stream>>>(stats, g3, be3, bnp, 1.f / (float)N);
    bnapply_kernel<<<NHB, 256, 0, stream>>>(Z, bnp, A, (int)NH);

    // --- layer 4 (no act/BN) ---
    hipMemsetAsync(T1, 0, NH * 4, stream);
    prop128_kernel<<<PB, 256, 0, stream>>>(A, w, src, dst, T1, 1.f, E);
    neg_kernel<<<NHB, 256, 0, stream>>>(A, T2, (int)NH);
    prop128_kernel<<<PB, 256, 0, stream>>>(T1, w, src, dst, T2, 2.f, E);
    neg_kernel<<<NHB, 256, 0, stream>>>(T1, T3, (int)NH);
    prop128_kernel<<<PB, 256, 0, stream>>>(T2, w, src, dst, T3, 2.f, E);
    gemm_cheb<0, 0><<<GB, 256, 0, stream>>>(A, T1, T2, T3, W4, b4, Z, nullptr, N);

    // --- normalize + project ---
    final_kernel<<<(N * 64 + 255) / 256, 256, 0, stream>>>(Z, Wm, bm, out, N);
}

// Round 2
// 1580.121 us; speedup vs baseline: 2.9764x; 2.9764x over previous
//
#include <hip/hip_runtime.h>
#include <math.h>

#define HDIM 128

// ---------------- degree / CSR build ----------------

__global__ void degs_kernel(const int* __restrict__ src, const int* __restrict__ dst,
                            int* __restrict__ degS, int* __restrict__ degD, int E) {
    int e = blockIdx.x * blockDim.x + threadIdx.x;
    if (e < E) {
        atomicAdd(&degS[src[e]], 1);
        atomicAdd(&degD[dst[e]], 1);
    }
}

__global__ void dinv_kernel(const int* __restrict__ degS, float* __restrict__ dinv, int N) {
    int i = blockIdx.x * blockDim.x + threadIdx.x;
    if (i < N) { int d = degS[i]; dinv[i] = d > 0 ? rsqrtf((float)d) : 0.f; }
}

// single-block exclusive scan of degD -> rp[0..N], rp[N] = E
__global__ __launch_bounds__(1024)
void scan_kernel(const int* __restrict__ deg, int* __restrict__ rp, int N) {
    __shared__ int part[1024];
    int tid = threadIdx.x;
    int chunk = (N + 1023) / 1024;
    int start = tid * chunk;
    int end = start + chunk; if (end > N) end = N;
    int s = 0;
    for (int i = start; i < end; ++i) s += deg[i];
    part[tid] = s;
    __syncthreads();
    for (int off = 1; off < 1024; off <<= 1) {
        int v = (tid >= off) ? part[tid - off] : 0;
        __syncthreads();
        part[tid] += v;
        __syncthreads();
    }
    int run = (tid == 0) ? 0 : part[tid - 1];
    for (int i = start; i < end; ++i) { rp[i] = run; run += deg[i]; }
    if (start < N && end == N) rp[N] = run;
}

__global__ void scatter_kernel(const int* __restrict__ src, const int* __restrict__ dst,
                               const float* __restrict__ dinv, const int* __restrict__ rp,
                               int* __restrict__ cursor, int2* __restrict__ ev, int E) {
    int e = blockIdx.x * blockDim.x + threadIdx.x;
    if (e >= E) return;
    int s = src[e], d = dst[e];
    float w = -dinv[s] * dinv[d];
    int pos = atomicAdd(&cursor[d], 1);
    ev[rp[d] + pos] = make_int2(s, __float_as_int(w));
}

// ---------------- pull propagation ----------------
// out[i] = alpha * sum_{e in CSR[i]} w*t[src] - (prev ? prev[i] : 0)
__global__ __launch_bounds__(256)
void pull128(const float* __restrict__ t, const float* __restrict__ prev,
             const int* __restrict__ rp, const int2* __restrict__ ev,
             float* __restrict__ outp, float alpha, int N) {
    int node = blockIdx.x * 4 + (threadIdx.x >> 6);
    if (node >= N) return;
    int lane = threadIdx.x & 63;
    int b = rp[node], e = rp[node + 1];
    float a0 = 0.f, a1 = 0.f;
    for (int j = b; j < e; ++j) {
        int2 sw = ev[j];
        float w = __int_as_float(sw.y);
        float2 rv = *(const float2*)(t + (size_t)sw.x * HDIM + 2 * lane);
        a0 += w * rv.x;
        a1 += w * rv.y;
    }
    size_t o = (size_t)node * HDIM + 2 * lane;
    float r0 = alpha * a0, r1 = alpha * a1;
    if (prev) { r0 -= prev[o]; r1 -= prev[o + 1]; }
    *(float2*)(outp + o) = make_float2(r0, r1);
}

__global__ void pull3(const float* __restrict__ t, const float* __restrict__ prev,
                      const int* __restrict__ rp, const int2* __restrict__ ev,
                      float* __restrict__ outp, float alpha, int N) {
    int node = blockIdx.x * blockDim.x + threadIdx.x;
    if (node >= N) return;
    int b = rp[node], e = rp[node + 1];
    float a0 = 0.f, a1 = 0.f, a2 = 0.f;
    for (int j = b; j < e; ++j) {
        int2 sw = ev[j];
        float w = __int_as_float(sw.y);
        const float* r = t + (size_t)sw.x * 3;
        a0 += w * r[0]; a1 += w * r[1]; a2 += w * r[2];
    }
    float r0 = alpha * a0, r1 = alpha * a1, r2 = alpha * a2;
    if (prev) {
        r0 -= prev[node * 3 + 0];
        r1 -= prev[node * 3 + 1];
        r2 -= prev[node * 3 + 2];
    }
    outp[node * 3 + 0] = r0;
    outp[node * 3 + 1] = r1;
    outp[node * 3 + 2] = r2;
}

// ---------------- fused Cheb GEMM: Z = sum_k T_k @ W_k + b, act, BN-stats ----------------
// ACT: 0 none, 1 leaky(0.01), 2 relu.  STATS: accumulate per-column sum/sumsq.
template <int ACT, int STATS>
__global__ __launch_bounds__(256)
void gemm_cheb(const float* __restrict__ T0, const float* __restrict__ T1,
               const float* __restrict__ T2, const float* __restrict__ T3,
               const float* __restrict__ W, const float* __restrict__ bias,
               float* __restrict__ out, float* __restrict__ stats, int N) {
    __shared__ float As[8][128];
    __shared__ float Bs[8][128];
    __shared__ float s_sum[128];
    __shared__ float s_sq[128];
    int tid = threadIdx.x;
    int tx = tid & 15, ty = tid >> 4;
    int row0 = blockIdx.x * 128;
    float acc[8][8] = {};
    const float* Ts[4] = {T0, T1, T2, T3};
    if (STATS && tid < 128) { s_sum[tid] = 0.f; s_sq[tid] = 0.f; }

    int ar = tid >> 1;            // A row 0..127
    int ac = (tid & 1) * 4;       // A col offset 0 or 4
    int br = tid >> 5;            // B row 0..7
    int bc = (tid * 4) & 127;     // B col

    for (int sel = 0; sel < 4; ++sel) {
        const float* __restrict__ Tp = Ts[sel];
        const float* __restrict__ Wp = W + sel * 128 * 128;
        for (int kt = 0; kt < 16; ++kt) {
            int k0 = kt * 8;
            __syncthreads();
            float4 av = make_float4(0.f, 0.f, 0.f, 0.f);
            if (row0 + ar < N)
                av = *(const float4*)(Tp + (size_t)(row0 + ar) * 128 + k0 + ac);
            As[ac + 0][ar] = av.x; As[ac + 1][ar] = av.y;
            As[ac + 2][ar] = av.z; As[ac + 3][ar] = av.w;
            float4 bv = *(const float4*)(Wp + (size_t)(k0 + br) * 128 + bc);
            *(float4*)(&Bs[br][bc]) = bv;
            __syncthreads();
#pragma unroll
            for (int kk = 0; kk < 8; ++kk) {
                float a[8], b[8];
#pragma unroll
                for (int i = 0; i < 8; ++i) a[i] = As[kk][ty * 8 + i];
#pragma unroll
                for (int j = 0; j < 8; ++j) b[j] = Bs[kk][tx * 8 + j];
#pragma unroll
                for (int i = 0; i < 8; ++i)
#pragma unroll
                    for (int j = 0; j < 8; ++j) acc[i][j] += a[i] * b[j];
            }
        }
    }

    float csum[8] = {}, csq[8] = {};
#pragma unroll
    for (int i = 0; i < 8; ++i) {
        int r = row0 + ty * 8 + i;
        if (r < N) {
#pragma unroll
            for (int j = 0; j < 8; ++j) {
                int c = tx * 8 + j;
                float v = acc[i][j] + bias[c];
                if (ACT == 1) v = v >= 0.f ? v : 0.01f * v;
                else if (ACT == 2) v = fmaxf(v, 0.f);
                out[(size_t)r * 128 + c] = v;
                if (STATS) { csum[j] += v; csq[j] += v * v; }
            }
        }
    }
    if (STATS) {
#pragma unroll
        for (int j = 0; j < 8; ++j) {
            atomicAdd(&s_sum[tx * 8 + j], csum[j]);
            atomicAdd(&s_sq[tx * 8 + j], csq[j]);
        }
        __syncthreads();
        if (tid < 128) {
            atomicAdd(&stats[tid], s_sum[tid]);
            atomicAdd(&stats[128 + tid], s_sq[tid]);
        }
    }
}

// ---------------- layer-1 (input dim 3) fused GEMM, grid-stride ----------------
__global__ __launch_bounds__(256)
void gemm1_kernel(const float* __restrict__ x, const float* __restrict__ t1,
                  const float* __restrict__ t2, const float* __restrict__ t3,
                  const float* __restrict__ W1, const float* __restrict__ b1,
                  float* __restrict__ out, float* __restrict__ stats, int N) {
    __shared__ float s_sum[128];
    __shared__ float s_sq[128];
    int tid = threadIdx.x;
    int c = tid & 127;
    if (tid < 128) { s_sum[tid] = 0.f; s_sq[tid] = 0.f; }
    __syncthreads();
    float wreg[12];
#pragma unroll
    for (int i = 0; i < 12; ++i) wreg[i] = W1[i * 128 + c];
    float bias = b1[c];
    const float* Ts[4] = {x, t1, t2, t3};
    float lsum = 0.f, lsq = 0.f;
    for (int row = blockIdx.x * 2 + (tid >> 7); row < N; row += gridDim.x * 2) {
        float v = bias;
#pragma unroll
        for (int k = 0; k < 4; ++k) {
            const float* t = Ts[k];
#pragma unroll
            for (int d = 0; d < 3; ++d)
                v += t[row * 3 + d] * wreg[k * 3 + d];
        }
        v = v >= 0.f ? v : 0.01f * v;   // leaky_relu
        out[(size_t)row * 128 + c] = v;
        lsum += v; lsq += v * v;
    }
    atomicAdd(&s_sum[c], lsum);
    atomicAdd(&s_sq[c], lsq);
    __syncthreads();
    if (tid < 128) {
        atomicAdd(&stats[tid], s_sum[tid]);
        atomicAdd(&stats[128 + tid], s_sq[tid]);
    }
}

// ---------------- BN finalize + apply ----------------
__global__ void bnfin_kernel(const float* __restrict__ stats, const float* __restrict__ g,
                             const float* __restrict__ be, float* __restrict__ bnp, float invN) {
    int c = threadIdx.x;  // 128 threads
    float m = stats[c] * invN;
    float v = stats[128 + c] * invN - m * m;
    float sc = g[c] * rsqrtf(v + 1e-5f);
    bnp[c] = sc;
    bnp[128 + c] = be[c] - m * sc;
}

__global__ void bnapply_kernel(const float* __restrict__ z, const float* __restrict__ bnp,
                               float* __restrict__ outp, int n) {
    int i = blockIdx.x * blockDim.x + threadIdx.x;
    if (i < n) {
        int c = i & 127;
        outp[i] = z[i] * bnp[c] + bnp[128 + c];
    }
}

// ---------------- final: L2-normalize row + project to 3 ----------------
__global__ void final_kernel(const float* __restrict__ Z, const float* __restrict__ Wm,
                             const float* __restrict__ bm, float* __restrict__ out, int N) {
    int gid = blockIdx.x * blockDim.x + threadIdx.x;
    int node = gid >> 6;
    int lane = threadIdx.x & 63;
    if (node >= N) return;
    const float* z = Z + (size_t)node * 128;
    float z0 = z[lane], z1 = z[lane + 64];
    float sq = z0 * z0 + z1 * z1;
    float d0 = z0 * Wm[lane * 3 + 0] + z1 * Wm[(lane + 64) * 3 + 0];
    float d1 = z0 * Wm[lane * 3 + 1] + z1 * Wm[(lane + 64) * 3 + 1];
    float d2 = z0 * Wm[lane * 3 + 2] + z1 * Wm[(lane + 64) * 3 + 2];
#pragma unroll
    for (int off = 32; off > 0; off >>= 1) {
        sq += __shfl_down(sq, off);
        d0 += __shfl_down(d0, off);
        d1 += __shfl_down(d1, off);
        d2 += __shfl_down(d2, off);
    }
    if (lane == 0) {
        float inv = 1.f / fmaxf(sqrtf(sq), 1e-12f);
        out[node * 3 + 0] = d0 * inv + bm[0];
        out[node * 3 + 1] = d1 * inv + bm[1];
        out[node * 3 + 2] = d2 * inv + bm[2];
    }
}

// ---------------- host ----------------

extern "C" void kernel_launch(void* const* d_in, const int* in_sizes, int n_in,
                              void* d_out, int out_size, void* d_ws, size_t ws_size,
                              hipStream_t stream) {
    const float* x  = (const float*)d_in[0];
    const int*   ei = (const int*)d_in[1];
    const float* W1 = (const float*)d_in[2];
    const float* b1 = (const float*)d_in[3];
    const float* W2 = (const float*)d_in[4];
    const float* b2 = (const float*)d_in[5];
    const float* W3 = (const float*)d_in[6];
    const float* b3 = (const float*)d_in[7];
    const float* W4 = (const float*)d_in[8];
    const float* b4 = (const float*)d_in[9];
    const float* g1 = (const float*)d_in[10];
    const float* be1 = (const float*)d_in[11];
    const float* g2 = (const float*)d_in[12];
    const float* be2 = (const float*)d_in[13];
    const float* g3 = (const float*)d_in[14];
    const float* be3 = (const float*)d_in[15];
    const float* Wm = (const float*)d_in[16];
    const float* bm = (const float*)d_in[17];
    float* out = (float*)d_out;

    const int N = in_sizes[0] / 3;
    const int E = in_sizes[1] / 2;
    const size_t NH = (size_t)N * HDIM;
    const int* src = ei;
    const int* dst = ei + E;

    // ---- workspace layout (ints first, 8B-aligned ev, then floats) ----
    char* base = (char*)d_ws;
    int* degS   = (int*)base;            base += (size_t)N * 4;
    int* degD   = (int*)base;            base += (size_t)N * 4;
    int* cursor = (int*)base;            base += (size_t)N * 4;
    int* rp     = (int*)base;            base += (size_t)(N + 2) * 4;  // pad to even
    int2* ev    = (int2*)base;           base += (size_t)E * 8;
    float* dinv = (float*)base;          base += (size_t)N * 4;
    float* A    = (float*)base;          base += NH * 4;
    float* T1   = (float*)base;          base += NH * 4;
    float* T2   = (float*)base;          base += NH * 4;
    float* T3   = (float*)base;          base += NH * 4;
    float* Z    = (float*)base;          base += NH * 4;
    float* x1   = (float*)base;          base += (size_t)N * 3 * 4;
    float* x2   = (float*)base;          base += (size_t)N * 3 * 4;
    float* x3   = (float*)base;          base += (size_t)N * 3 * 4;
    float* stats = (float*)base;         base += 256 * 4;

    const int EB = (E + 255) / 256;
    const int NB = (N + 255) / 256;
    const int GB = (N + 127) / 128;       // gemm row tiles
    const int PB = (N + 3) / 4;           // pull128 blocks (4 nodes/block)
    const int NHB = (int)((NH + 255) / 256);
    const float invN = 1.f / (float)N;

    // --- CSR build + edge weights ---
    hipMemsetAsync(degS, 0, (size_t)N * 3 * 4, stream);   // degS, degD, cursor
    degs_kernel<<<EB, 256, 0, stream>>>(src, dst, degS, degD, E);
    dinv_kernel<<<NB, 256, 0, stream>>>(degS, dinv, N);
    scan_kernel<<<1, 1024, 0, stream>>>(degD, rp, N);
    scatter_kernel<<<EB, 256, 0, stream>>>(src, dst, dinv, rp, cursor, ev, E);

    // --- layer 1 (dim 3) ---
    pull3<<<NB, 256, 0, stream>>>(x,  nullptr, rp, ev, x1, 1.f, N);
    pull3<<<NB, 256, 0, stream>>>(x1, x,       rp, ev, x2, 2.f, N);
    pull3<<<NB, 256, 0, stream>>>(x2, x1,      rp, ev, x3, 2.f, N);
    hipMemsetAsync(stats, 0, 256 * 4, stream);
    gemm1_kernel<<<512, 256, 0, stream>>>(x, x1, x2, x3, W1, b1, Z, stats, N);
    bnfin_kernel<<<1, 128, 0, stream>>>(stats, g1, be1, stats, invN);  // bnp aliases stats tail? no:
    // NOTE: bnfin writes bnp into stats buffer itself (reads then writes same 256 floats,
    // single block, each thread reads its own slots before writing -> safe: it reads
    // stats[c] and stats[128+c] then writes bnp[c]=.. bnp[128+c]=..  same indices.
    bnapply_kernel<<<NHB, 256, 0, stream>>>(Z, stats, A, (int)NH);

    // --- layer 2 (leaky + BN) ---
    pull128<<<PB, 256, 0, stream>>>(A,  nullptr, rp, ev, T1, 1.f, N);
    pull128<<<PB, 256, 0, stream>>>(T1, A,       rp, ev, T2, 2.f, N);
    pull128<<<PB, 256, 0, stream>>>(T2, T1,      rp, ev, T3, 2.f, N);
    hipMemsetAsync(stats, 0, 256 * 4, stream);
    gemm_cheb<1, 1><<<GB, 256, 0, stream>>>(A, T1, T2, T3, W2, b2, Z, stats, N);
    bnfin_kernel<<<1, 128, 0, stream>>>(stats, g2, be2, stats, invN);
    bnapply_kernel<<<NHB, 256, 0, stream>>>(Z, stats, A, (int)NH);

    // --- layer 3 (relu + BN) ---
    pull128<<<PB, 256, 0, stream>>>(A,  nullptr, rp, ev, T1, 1.f, N);
    pull128<<<PB, 256, 0, stream>>>(T1, A,       rp, ev, T2, 2.f, N);
    pull128<<<PB, 256, 0, stream>>>(T2, T1,      rp, ev, T3, 2.f, N);
    hipMemsetAsync(stats, 0, 256 * 4, stream);
    gemm_cheb<2, 1><<<GB, 256, 0, stream>>>(A, T1, T2, T3, W3, b3, Z, stats, N);
    bnfin_kernel<<<1, 128, 0, stream>>>(stats, g3, be3, stats, invN);
    bnapply_kernel<<<NHB, 256, 0, stream>>>(Z, stats, A, (int)NH);

    // --- layer 4 (no act/BN) ---
    pull128<<<PB, 256, 0, stream>>>(A,  nullptr, rp, ev, T1, 1.f, N);
    pull128<<<PB, 256, 0, stream>>>(T1, A,       rp, ev, T2, 2.f, N);
    pull128<<<PB, 256, 0, stream>>>(T2, T1,      rp, ev, T3, 2.f, N);
    gemm_cheb<0, 0><<<GB, 256, 0, stream>>>(A, T1, T2, T3, W4, b4, Z, nullptr, N);

    // --- normalize + project ---
    final_kernel<<<(N * 64 + 255) / 256, 256, 0, stream>>>(Z, Wm, bm, out, N);
}

// Round 3
// 1432.192 us; speedup vs baseline: 3.2839x; 1.1033x over previous
//
#include <hip/hip_runtime.h>
#include <math.h>

#define HDIM 128

// ---------------- degree / CSR build ----------------

__global__ void degs_kernel(const int* __restrict__ src, const int* __restrict__ dst,
                            int* __restrict__ degS, int* __restrict__ degD, int E) {
    int e = blockIdx.x * blockDim.x + threadIdx.x;
    if (e < E) {
        atomicAdd(&degS[src[e]], 1);
        atomicAdd(&degD[dst[e]], 1);
    }
}

__global__ void dinv_kernel(const int* __restrict__ degS, float* __restrict__ dinv, int N) {
    int i = blockIdx.x * blockDim.x + threadIdx.x;
    if (i < N) { int d = degS[i]; dinv[i] = d > 0 ? rsqrtf((float)d) : 0.f; }
}

// single-block exclusive scan of degD -> rp[0..N], rp[N] = E
__global__ __launch_bounds__(1024)
void scan_kernel(const int* __restrict__ deg, int* __restrict__ rp, int N) {
    __shared__ int part[1024];
    int tid = threadIdx.x;
    int chunk = (N + 1023) / 1024;
    int start = tid * chunk;
    int end = start + chunk; if (end > N) end = N;
    int s = 0;
    for (int i = start; i < end; ++i) s += deg[i];
    part[tid] = s;
    __syncthreads();
    for (int off = 1; off < 1024; off <<= 1) {
        int v = (tid >= off) ? part[tid - off] : 0;
        __syncthreads();
        part[tid] += v;
        __syncthreads();
    }
    int run = (tid == 0) ? 0 : part[tid - 1];
    for (int i = start; i < end; ++i) { rp[i] = run; run += deg[i]; }
    if (start < N && end == N) rp[N] = run;
}

__global__ void scatter_kernel(const int* __restrict__ src, const int* __restrict__ dst,
                               const float* __restrict__ dinv, const int* __restrict__ rp,
                               int* __restrict__ cursor, int2* __restrict__ ev, int E) {
    int e = blockIdx.x * blockDim.x + threadIdx.x;
    if (e >= E) return;
    int s = src[e], d = dst[e];
    float w = -dinv[s] * dinv[d];
    int pos = atomicAdd(&cursor[d], 1);
    ev[rp[d] + pos] = make_int2(s, __float_as_int(w));
}

// ---------------- pull propagation ----------------
// out[i] = alpha * sum_{e in CSR[i]} w*t[src] - (prev ? prev[i] : 0)
// Unrolled x4: 4 independent gathers in flight per wave (latency hiding).
__global__ __launch_bounds__(256)
void pull128(const float* __restrict__ t, const float* __restrict__ prev,
             const int* __restrict__ rp, const int2* __restrict__ ev,
             float* __restrict__ outp, float alpha, int N) {
    int node = blockIdx.x * 4 + (threadIdx.x >> 6);
    if (node >= N) return;
    int lane = threadIdx.x & 63;
    int b = rp[node], e = rp[node + 1];
    float a00 = 0.f, a01 = 0.f, a10 = 0.f, a11 = 0.f;
    float a20 = 0.f, a21 = 0.f, a30 = 0.f, a31 = 0.f;
    int j = b;
    for (; j + 4 <= e; j += 4) {
        int2 s0 = ev[j], s1 = ev[j + 1], s2 = ev[j + 2], s3 = ev[j + 3];
        float2 r0 = *(const float2*)(t + (size_t)s0.x * HDIM + 2 * lane);
        float2 r1 = *(const float2*)(t + (size_t)s1.x * HDIM + 2 * lane);
        float2 r2 = *(const float2*)(t + (size_t)s2.x * HDIM + 2 * lane);
        float2 r3 = *(const float2*)(t + (size_t)s3.x * HDIM + 2 * lane);
        float w0 = __int_as_float(s0.y), w1 = __int_as_float(s1.y);
        float w2 = __int_as_float(s2.y), w3 = __int_as_float(s3.y);
        a00 += w0 * r0.x; a01 += w0 * r0.y;
        a10 += w1 * r1.x; a11 += w1 * r1.y;
        a20 += w2 * r2.x; a21 += w2 * r2.y;
        a30 += w3 * r3.x; a31 += w3 * r3.y;
    }
    for (; j < e; ++j) {
        int2 s0 = ev[j];
        float w0 = __int_as_float(s0.y);
        float2 r0 = *(const float2*)(t + (size_t)s0.x * HDIM + 2 * lane);
        a00 += w0 * r0.x; a01 += w0 * r0.y;
    }
    float v0 = (a00 + a10) + (a20 + a30);
    float v1 = (a01 + a11) + (a21 + a31);
    size_t o = (size_t)node * HDIM + 2 * lane;
    float r0 = alpha * v0, r1 = alpha * v1;
    if (prev) { r0 -= prev[o]; r1 -= prev[o + 1]; }
    *(float2*)(outp + o) = make_float2(r0, r1);
}

__global__ void pull3(const float* __restrict__ t, const float* __restrict__ prev,
                      const int* __restrict__ rp, const int2* __restrict__ ev,
                      float* __restrict__ outp, float alpha, int N) {
    int node = blockIdx.x * blockDim.x + threadIdx.x;
    if (node >= N) return;
    int b = rp[node], e = rp[node + 1];
    float a0 = 0.f, a1 = 0.f, a2 = 0.f;
    for (int j = b; j < e; ++j) {
        int2 sw = ev[j];
        float w = __int_as_float(sw.y);
        const float* r = t + (size_t)sw.x * 3;
        a0 += w * r[0]; a1 += w * r[1]; a2 += w * r[2];
    }
    float r0 = alpha * a0, r1 = alpha * a1, r2 = alpha * a2;
    if (prev) {
        r0 -= prev[node * 3 + 0];
        r1 -= prev[node * 3 + 1];
        r2 -= prev[node * 3 + 2];
    }
    outp[node * 3 + 0] = r0;
    outp[node * 3 + 1] = r1;
    outp[node * 3 + 2] = r2;
}

// ---------------- fused Cheb GEMM: Z = sum_k T_k @ W_k + b, act, BN-stats ----
// 64x128 tile, BK=16, double-buffered LDS, one sync per K-tile.
// ACT: 0 none, 1 leaky(0.01), 2 relu.  STATS: accumulate per-column sum/sumsq.
template <int ACT, int STATS>
__global__ __launch_bounds__(256)
void gemm_cheb(const float* __restrict__ T0c, const float* __restrict__ T1c,
               const float* __restrict__ T2c, const float* __restrict__ T3c,
               const float* __restrict__ W, const float* __restrict__ bias,
               float* __restrict__ out, float* __restrict__ stats, int N) {
    // stride 68 floats = 272B: 16B-aligned rows AND <=2-way bank aliasing on writes
    __shared__ float As[2][16][68];
    __shared__ float Bs[2][16][128];
    __shared__ float s_sum[128];
    __shared__ float s_sq[128];

    int tid = threadIdx.x;
    int tx = tid & 31;            // col group: cols tx*4 .. tx*4+3
    int rg = tid >> 5;            // row group: rows rg*8 .. rg*8+7
    int row0 = blockIdx.x * 64;

    int ar = tid >> 2;            // A load: row 0..63
    int akc = (tid & 3) * 4;      // A load: k offset 0/4/8/12
    int bkr = tid >> 4;           // B load: k row 0..15
    int bcc = (tid & 15) * 8;     // B load: col 0..120

    const float* Ts[4] = {T0c, T1c, T2c, T3c};
    float acc[8][4] = {};
    if (STATS && tid < 128) { s_sum[tid] = 0.f; s_sq[tid] = 0.f; }

    bool arow_ok = (row0 + ar) < N;
    const float* arow_base = Ts[0] + (size_t)(row0 + (arow_ok ? ar : 0)) * HDIM;

    // prologue: tile 0 (sel=0, kin=0)
    float4 av = arow_ok ? *(const float4*)(arow_base + akc) : make_float4(0, 0, 0, 0);
    float4 bv0 = *(const float4*)(W + bkr * 128 + bcc);
    float4 bv1 = *(const float4*)(W + bkr * 128 + bcc + 4);
    As[0][akc + 0][ar] = av.x; As[0][akc + 1][ar] = av.y;
    As[0][akc + 2][ar] = av.z; As[0][akc + 3][ar] = av.w;
    *(float4*)&Bs[0][bkr][bcc] = bv0;
    *(float4*)&Bs[0][bkr][bcc + 4] = bv1;
    __syncthreads();

    for (int kt = 0; kt < 32; ++kt) {
        int buf = kt & 1;
        if (kt < 31) {
            int sel = (kt + 1) >> 3;
            int kin = ((kt + 1) & 7) * 16;
            const float* Tp = Ts[sel];
            av = arow_ok ? *(const float4*)(Tp + (size_t)(row0 + ar) * HDIM + kin + akc)
                         : make_float4(0, 0, 0, 0);
            const float* Wp = W + sel * 16384 + (size_t)kin * 128;
            bv0 = *(const float4*)(Wp + bkr * 128 + bcc);
            bv1 = *(const float4*)(Wp + bkr * 128 + bcc + 4);
        }
#pragma unroll
        for (int k = 0; k < 16; ++k) {
            float a[8], b[4];
            *(float4*)&a[0] = *(const float4*)&As[buf][k][rg * 8];
            *(float4*)&a[4] = *(const float4*)&As[buf][k][rg * 8 + 4];
            *(float4*)&b[0] = *(const float4*)&Bs[buf][k][tx * 4];
#pragma unroll
            for (int i = 0; i < 8; ++i)
#pragma unroll
                for (int j = 0; j < 4; ++j) acc[i][j] += a[i] * b[j];
        }
        if (kt < 31) {
            int nb = buf ^ 1;
            As[nb][akc + 0][ar] = av.x; As[nb][akc + 1][ar] = av.y;
            As[nb][akc + 2][ar] = av.z; As[nb][akc + 3][ar] = av.w;
            *(float4*)&Bs[nb][bkr][bcc] = bv0;
            *(float4*)&Bs[nb][bkr][bcc + 4] = bv1;
            __syncthreads();
        }
    }

    // epilogue
    float b4v[4];
#pragma unroll
    for (int j = 0; j < 4; ++j) b4v[j] = bias[tx * 4 + j];
    float csum[4] = {}, csq[4] = {};
#pragma unroll
    for (int i = 0; i < 8; ++i) {
        int r = row0 + rg * 8 + i;
        if (r < N) {
            float4 vv;
            float* vp = (float*)&vv;
#pragma unroll
            for (int j = 0; j < 4; ++j) {
                float v = acc[i][j] + b4v[j];
                if (ACT == 1) v = v >= 0.f ? v : 0.01f * v;
                else if (ACT == 2) v = fmaxf(v, 0.f);
                vp[j] = v;
                if (STATS) { csum[j] += v; csq[j] += v * v; }
            }
            *(float4*)(out + (size_t)r * HDIM + tx * 4) = vv;
        }
    }
    if (STATS) {
        __syncthreads();
#pragma unroll
        for (int j = 0; j < 4; ++j) {
            atomicAdd(&s_sum[tx * 4 + j], csum[j]);
            atomicAdd(&s_sq[tx * 4 + j], csq[j]);
        }
        __syncthreads();
        if (tid < 128) {
            atomicAdd(&stats[tid], s_sum[tid]);
            atomicAdd(&stats[128 + tid], s_sq[tid]);
        }
    }
}

// ---------------- layer-1 (input dim 3) fused GEMM, grid-stride ----------------
__global__ __launch_bounds__(256)
void gemm1_kernel(const float* __restrict__ x, const float* __restrict__ t1,
                  const float* __restrict__ t2, const float* __restrict__ t3,
                  const float* __restrict__ W1, const float* __restrict__ b1,
                  float* __restrict__ out, float* __restrict__ stats, int N) {
    __shared__ float s_sum[128];
    __shared__ float s_sq[128];
    int tid = threadIdx.x;
    int c = tid & 127;
    if (tid < 128) { s_sum[tid] = 0.f; s_sq[tid] = 0.f; }
    __syncthreads();
    float wreg[12];
#pragma unroll
    for (int i = 0; i < 12; ++i) wreg[i] = W1[i * 128 + c];
    float bias = b1[c];
    const float* Ts[4] = {x, t1, t2, t3};
    float lsum = 0.f, lsq = 0.f;
    for (int row = blockIdx.x * 2 + (tid >> 7); row < N; row += gridDim.x * 2) {
        float v = bias;
#pragma unroll
        for (int k = 0; k < 4; ++k) {
            const float* t = Ts[k];
#pragma unroll
            for (int d = 0; d < 3; ++d)
                v += t[row * 3 + d] * wreg[k * 3 + d];
        }
        v = v >= 0.f ? v : 0.01f * v;   // leaky_relu
        out[(size_t)row * HDIM + c] = v;
        lsum += v; lsq += v * v;
    }
    atomicAdd(&s_sum[c], lsum);
    atomicAdd(&s_sq[c], lsq);
    __syncthreads();
    if (tid < 128) {
        atomicAdd(&stats[tid], s_sum[tid]);
        atomicAdd(&stats[128 + tid], s_sq[tid]);
    }
}

// ---------------- BN finalize + apply ----------------
__global__ void bnfin_kernel(const float* __restrict__ stats, const float* __restrict__ g,
                             const float* __restrict__ be, float* __restrict__ bnp, float invN) {
    int c = threadIdx.x;  // 128 threads
    float m = stats[c] * invN;
    float v = stats[128 + c] * invN - m * m;
    float sc = g[c] * rsqrtf(v + 1e-5f);
    bnp[c] = sc;
    bnp[128 + c] = be[c] - m * sc;
}

__global__ void bnapply_kernel(const float* __restrict__ z, const float* __restrict__ bnp,
                               float* __restrict__ outp, int n) {
    int i = blockIdx.x * blockDim.x + threadIdx.x;
    if (i < n) {
        int c = i & 127;
        outp[i] = z[i] * bnp[c] + bnp[128 + c];
    }
}

// ---------------- final: L2-normalize row + project to 3 ----------------
__global__ void final_kernel(const float* __restrict__ Z, const float* __restrict__ Wm,
                             const float* __restrict__ bm, float* __restrict__ out, int N) {
    int gid = blockIdx.x * blockDim.x + threadIdx.x;
    int node = gid >> 6;
    int lane = threadIdx.x & 63;
    if (node >= N) return;
    const float* z = Z + (size_t)node * HDIM;
    float z0 = z[lane], z1 = z[lane + 64];
    float sq = z0 * z0 + z1 * z1;
    float d0 = z0 * Wm[lane * 3 + 0] + z1 * Wm[(lane + 64) * 3 + 0];
    float d1 = z0 * Wm[lane * 3 + 1] + z1 * Wm[(lane + 64) * 3 + 1];
    float d2 = z0 * Wm[lane * 3 + 2] + z1 * Wm[(lane + 64) * 3 + 2];
#pragma unroll
    for (int off = 32; off > 0; off >>= 1) {
        sq += __shfl_down(sq, off);
        d0 += __shfl_down(d0, off);
        d1 += __shfl_down(d1, off);
        d2 += __shfl_down(d2, off);
    }
    if (lane == 0) {
        float inv = 1.f / fmaxf(sqrtf(sq), 1e-12f);
        out[node * 3 + 0] = d0 * inv + bm[0];
        out[node * 3 + 1] = d1 * inv + bm[1];
        out[node * 3 + 2] = d2 * inv + bm[2];
    }
}

// ---------------- host ----------------

extern "C" void kernel_launch(void* const* d_in, const int* in_sizes, int n_in,
                              void* d_out, int out_size, void* d_ws, size_t ws_size,
                              hipStream_t stream) {
    const float* x  = (const float*)d_in[0];
    const int*   ei = (const int*)d_in[1];
    const float* W1 = (const float*)d_in[2];
    const float* b1 = (const float*)d_in[3];
    const float* W2 = (const float*)d_in[4];
    const float* b2 = (const float*)d_in[5];
    const float* W3 = (const float*)d_in[6];
    const float* b3 = (const float*)d_in[7];
    const float* W4 = (const float*)d_in[8];
    const float* b4 = (const float*)d_in[9];
    const float* g1 = (const float*)d_in[10];
    const float* be1 = (const float*)d_in[11];
    const float* g2 = (const float*)d_in[12];
    const float* be2 = (const float*)d_in[13];
    const float* g3 = (const float*)d_in[14];
    const float* be3 = (const float*)d_in[15];
    const float* Wm = (const float*)d_in[16];
    const float* bm = (const float*)d_in[17];
    float* out = (float*)d_out;

    const int N = in_sizes[0] / 3;
    const int E = in_sizes[1] / 2;
    const size_t NH = (size_t)N * HDIM;
    const int* src = ei;
    const int* dst = ei + E;

    // ---- workspace layout ----
    char* base = (char*)d_ws;
    int* degS   = (int*)base;            base += (size_t)N * 4;
    int* degD   = (int*)base;            base += (size_t)N * 4;
    int* cursor = (int*)base;            base += (size_t)N * 4;
    int* rp     = (int*)base;            base += (size_t)(N + 2) * 4;
    int2* ev    = (int2*)base;           base += (size_t)E * 8;
    float* dinv = (float*)base;          base += (size_t)N * 4;
    float* A    = (float*)base;          base += NH * 4;
    float* T1   = (float*)base;          base += NH * 4;
    float* T2   = (float*)base;          base += NH * 4;
    float* T3   = (float*)base;          base += NH * 4;
    float* Z    = (float*)base;          base += NH * 4;
    float* x1   = (float*)base;          base += (size_t)N * 3 * 4;
    float* x2   = (float*)base;          base += (size_t)N * 3 * 4;
    float* x3   = (float*)base;          base += (size_t)N * 3 * 4;
    float* stats = (float*)base;         base += 256 * 4;

    const int EB = (E + 255) / 256;
    const int NB = (N + 255) / 256;
    const int GB = (N + 63) / 64;         // gemm row tiles (64 rows)
    const int PB = (N + 3) / 4;           // pull128 blocks (4 nodes/block)
    const int NHB = (int)((NH + 255) / 256);
    const float invN = 1.f / (float)N;

    // --- CSR build + edge weights ---
    hipMemsetAsync(degS, 0, (size_t)N * 3 * 4, stream);   // degS, degD, cursor
    degs_kernel<<<EB, 256, 0, stream>>>(src, dst, degS, degD, E);
    dinv_kernel<<<NB, 256, 0, stream>>>(degS, dinv, N);
    scan_kernel<<<1, 1024, 0, stream>>>(degD, rp, N);
    scatter_kernel<<<EB, 256, 0, stream>>>(src, dst, dinv, rp, cursor, ev, E);

    // --- layer 1 (dim 3) ---
    pull3<<<NB, 256, 0, stream>>>(x,  nullptr, rp, ev, x1, 1.f, N);
    pull3<<<NB, 256, 0, stream>>>(x1, x,       rp, ev, x2, 2.f, N);
    pull3<<<NB, 256, 0, stream>>>(x2, x1,      rp, ev, x3, 2.f, N);
    hipMemsetAsync(stats, 0, 256 * 4, stream);
    gemm1_kernel<<<512, 256, 0, stream>>>(x, x1, x2, x3, W1, b1, Z, stats, N);
    bnfin_kernel<<<1, 128, 0, stream>>>(stats, g1, be1, stats, invN);
    bnapply_kernel<<<NHB, 256, 0, stream>>>(Z, stats, A, (int)NH);

    // --- layer 2 (leaky + BN) ---
    pull128<<<PB, 256, 0, stream>>>(A,  nullptr, rp, ev, T1, 1.f, N);
    pull128<<<PB, 256, 0, stream>>>(T1, A,       rp, ev, T2, 2.f, N);
    pull128<<<PB, 256, 0, stream>>>(T2, T1,      rp, ev, T3, 2.f, N);
    hipMemsetAsync(stats, 0, 256 * 4, stream);
    gemm_cheb<1, 1><<<GB, 256, 0, stream>>>(A, T1, T2, T3, W2, b2, Z, stats, N);
    bnfin_kernel<<<1, 128, 0, stream>>>(stats, g2, be2, stats, invN);
    bnapply_kernel<<<NHB, 256, 0, stream>>>(Z, stats, A, (int)NH);

    // --- layer 3 (relu + BN) ---
    pull128<<<PB, 256, 0, stream>>>(A,  nullptr, rp, ev, T1, 1.f, N);
    pull128<<<PB, 256, 0, stream>>>(T1, A,       rp, ev, T2, 2.f, N);
    pull128<<<PB, 256, 0, stream>>>(T2, T1,      rp, ev, T3, 2.f, N);
    hipMemsetAsync(stats, 0, 256 * 4, stream);
    gemm_cheb<2, 1><<<GB, 256, 0, stream>>>(A, T1, T2, T3, W3, b3, Z, stats, N);
    bnfin_kernel<<<1, 128, 0, stream>>>(stats, g3, be3, stats, invN);
    bnapply_kernel<<<NHB, 256, 0, stream>>>(Z, stats, A, (int)NH);

    // --- layer 4 (no act/BN) ---
    pull128<<<PB, 256, 0, stream>>>(A,  nullptr, rp, ev, T1, 1.f, N);
    pull128<<<PB, 256, 0, stream>>>(T1, A,       rp, ev, T2, 2.f, N);
    pull128<<<PB, 256, 0, stream>>>(T2, T1,      rp, ev, T3, 2.f, N);
    gemm_cheb<0, 0><<<GB, 256, 0, stream>>>(A, T1, T2, T3, W4, b4, Z, nullptr, N);

    // --- normalize + project ---
    final_kernel<<<(N * 64 + 255) / 256, 256, 0, stream>>>(Z, Wm, bm, out, N);
}

// Round 4
// 1371.393 us; speedup vs baseline: 3.4295x; 1.0443x over previous
//
#include <hip/hip_runtime.h>
#include <math.h>

#define HDIM 128

// ---------------- degree / CSR build ----------------

__global__ void degs_kernel(const int* __restrict__ src, const int* __restrict__ dst,
                            int* __restrict__ degS, int* __restrict__ degD, int E) {
    int e = blockIdx.x * blockDim.x + threadIdx.x;
    if (e < E) {
        atomicAdd(&degS[src[e]], 1);
        atomicAdd(&degD[dst[e]], 1);
    }
}

__global__ void dinv_kernel(const int* __restrict__ degS, float* __restrict__ dinv, int N) {
    int i = blockIdx.x * blockDim.x + threadIdx.x;
    if (i < N) { int d = degS[i]; dinv[i] = d > 0 ? rsqrtf((float)d) : 0.f; }
}

// single-block exclusive scan of degD -> rp[0..N], rp[N] = E
__global__ __launch_bounds__(1024)
void scan_kernel(const int* __restrict__ deg, int* __restrict__ rp, int N) {
    __shared__ int part[1024];
    int tid = threadIdx.x;
    int chunk = (N + 1023) / 1024;
    int start = tid * chunk;
    int end = start + chunk; if (end > N) end = N;
    int s = 0;
    for (int i = start; i < end; ++i) s += deg[i];
    part[tid] = s;
    __syncthreads();
    for (int off = 1; off < 1024; off <<= 1) {
        int v = (tid >= off) ? part[tid - off] : 0;
        __syncthreads();
        part[tid] += v;
        __syncthreads();
    }
    int run = (tid == 0) ? 0 : part[tid - 1];
    for (int i = start; i < end; ++i) { rp[i] = run; run += deg[i]; }
    if (start < N && end == N) rp[N] = run;
}

__global__ void scatter_kernel(const int* __restrict__ src, const int* __restrict__ dst,
                               const float* __restrict__ dinv, const int* __restrict__ rp,
                               int* __restrict__ cursor, int2* __restrict__ ev, int E) {
    int e = blockIdx.x * blockDim.x + threadIdx.x;
    if (e >= E) return;
    int s = src[e], d = dst[e];
    float w = -dinv[s] * dinv[d];
    int pos = atomicAdd(&cursor[d], 1);
    ev[rp[d] + pos] = make_int2(s, __float_as_int(w));
}

// ---------------- pull propagation (float4, 2 edges per wave, x4 unroll) ----
// out[i] = alpha * sum_{e in CSR[i]} w * g(t[src]) - p(prev[i])
//   GBN: g(v) = v*scale+shift (BN applied to gathered rows); then prev==null
//   !GBN: prev != null; PBN: p(v) = v*scale+shift else identity
template <int GBN, int PBN>
__global__ __launch_bounds__(256)
void pull128(const float* __restrict__ t, const int* __restrict__ rp,
             const int2* __restrict__ ev, const float* __restrict__ prev,
             const float* __restrict__ bnp, float* __restrict__ outp,
             float alpha, int N) {
    int node = blockIdx.x * 4 + (threadIdx.x >> 6);
    if (node >= N) return;
    int lane = threadIdx.x & 63;
    int c4 = (lane & 31) * 4;     // channel group
    int epar = lane >> 5;         // edge parity for this half-wave

    float4 sc = make_float4(1.f, 1.f, 1.f, 1.f);
    float4 sh = make_float4(0.f, 0.f, 0.f, 0.f);
    if (GBN || PBN) {
        sc = *(const float4*)(bnp + c4);
        sh = *(const float4*)(bnp + 128 + c4);
    }

    int b = rp[node], e = rp[node + 1];
    float4 a0 = {0,0,0,0}, a1 = {0,0,0,0}, a2 = {0,0,0,0}, a3 = {0,0,0,0};

    int j = b;
    for (; j + 8 <= e; j += 8) {
        int2 s0 = ev[j + 0 + epar];
        int2 s1 = ev[j + 2 + epar];
        int2 s2 = ev[j + 4 + epar];
        int2 s3 = ev[j + 6 + epar];
        float4 r0 = *(const float4*)(t + (size_t)s0.x * HDIM + c4);
        float4 r1 = *(const float4*)(t + (size_t)s1.x * HDIM + c4);
        float4 r2 = *(const float4*)(t + (size_t)s2.x * HDIM + c4);
        float4 r3 = *(const float4*)(t + (size_t)s3.x * HDIM + c4);
        float w0 = __int_as_float(s0.y), w1 = __int_as_float(s1.y);
        float w2 = __int_as_float(s2.y), w3 = __int_as_float(s3.y);
        if (GBN) {
            r0.x = r0.x * sc.x + sh.x; r0.y = r0.y * sc.y + sh.y; r0.z = r0.z * sc.z + sh.z; r0.w = r0.w * sc.w + sh.w;
            r1.x = r1.x * sc.x + sh.x; r1.y = r1.y * sc.y + sh.y; r1.z = r1.z * sc.z + sh.z; r1.w = r1.w * sc.w + sh.w;
            r2.x = r2.x * sc.x + sh.x; r2.y = r2.y * sc.y + sh.y; r2.z = r2.z * sc.z + sh.z; r2.w = r2.w * sc.w + sh.w;
            r3.x = r3.x * sc.x + sh.x; r3.y = r3.y * sc.y + sh.y; r3.z = r3.z * sc.z + sh.z; r3.w = r3.w * sc.w + sh.w;
        }
        a0.x += w0 * r0.x; a0.y += w0 * r0.y; a0.z += w0 * r0.z; a0.w += w0 * r0.w;
        a1.x += w1 * r1.x; a1.y += w1 * r1.y; a1.z += w1 * r1.z; a1.w += w1 * r1.w;
        a2.x += w2 * r2.x; a2.y += w2 * r2.y; a2.z += w2 * r2.z; a2.w += w2 * r2.w;
        a3.x += w3 * r3.x; a3.y += w3 * r3.y; a3.z += w3 * r3.z; a3.w += w3 * r3.w;
    }
    for (; j + 2 <= e; j += 2) {
        int2 s0 = ev[j + epar];
        float w0 = __int_as_float(s0.y);
        float4 r0 = *(const float4*)(t + (size_t)s0.x * HDIM + c4);
        if (GBN) {
            r0.x = r0.x * sc.x + sh.x; r0.y = r0.y * sc.y + sh.y; r0.z = r0.z * sc.z + sh.z; r0.w = r0.w * sc.w + sh.w;
        }
        a0.x += w0 * r0.x; a0.y += w0 * r0.y; a0.z += w0 * r0.z; a0.w += w0 * r0.w;
    }
    if (j < e && epar == 0) {   // odd leftover handled by low half-wave
        int2 s0 = ev[j];
        float w0 = __int_as_float(s0.y);
        float4 r0 = *(const float4*)(t + (size_t)s0.x * HDIM + c4);
        if (GBN) {
            r0.x = r0.x * sc.x + sh.x; r0.y = r0.y * sc.y + sh.y; r0.z = r0.z * sc.z + sh.z; r0.w = r0.w * sc.w + sh.w;
        }
        a1.x += w0 * r0.x; a1.y += w0 * r0.y; a1.z += w0 * r0.z; a1.w += w0 * r0.w;
    }

    float4 s4;
    s4.x = (a0.x + a1.x) + (a2.x + a3.x);
    s4.y = (a0.y + a1.y) + (a2.y + a3.y);
    s4.z = (a0.z + a1.z) + (a2.z + a3.z);
    s4.w = (a0.w + a1.w) + (a2.w + a3.w);
    s4.x += __shfl_xor(s4.x, 32);
    s4.y += __shfl_xor(s4.y, 32);
    s4.z += __shfl_xor(s4.z, 32);
    s4.w += __shfl_xor(s4.w, 32);

    if (lane < 32) {
        size_t o = (size_t)node * HDIM + c4;
        float4 r;
        r.x = alpha * s4.x; r.y = alpha * s4.y; r.z = alpha * s4.z; r.w = alpha * s4.w;
        if (!GBN) {
            float4 pv = *(const float4*)(prev + o);
            if (PBN) {
                pv.x = pv.x * sc.x + sh.x; pv.y = pv.y * sc.y + sh.y;
                pv.z = pv.z * sc.z + sh.z; pv.w = pv.w * sc.w + sh.w;
            }
            r.x -= pv.x; r.y -= pv.y; r.z -= pv.z; r.w -= pv.w;
        }
        *(float4*)(outp + o) = r;
    }
}

__global__ void pull3(const float* __restrict__ t, const float* __restrict__ prev,
                      const int* __restrict__ rp, const int2* __restrict__ ev,
                      float* __restrict__ outp, float alpha, int N) {
    int node = blockIdx.x * blockDim.x + threadIdx.x;
    if (node >= N) return;
    int b = rp[node], e = rp[node + 1];
    float a0 = 0.f, a1 = 0.f, a2 = 0.f;
    for (int j = b; j < e; ++j) {
        int2 sw = ev[j];
        float w = __int_as_float(sw.y);
        const float* r = t + (size_t)sw.x * 3;
        a0 += w * r[0]; a1 += w * r[1]; a2 += w * r[2];
    }
    float r0 = alpha * a0, r1 = alpha * a1, r2 = alpha * a2;
    if (prev) {
        r0 -= prev[node * 3 + 0];
        r1 -= prev[node * 3 + 1];
        r2 -= prev[node * 3 + 2];
    }
    outp[node * 3 + 0] = r0;
    outp[node * 3 + 1] = r1;
    outp[node * 3 + 2] = r2;
}

// ---------------- fused Cheb GEMM ------------------------------------------
// Z = BN(T0)@W0 + T1@W1 + T2@W2 + T3@W3 + b, act, BN-stats.
// 128x128 tile, BK=8, single LDS buffer (round-2 shape: 60 VGPR known-good),
// float4 LDS reads, float4 stores. T0 gets BN applied on tile load (bnp).
template <int ACT, int STATS>
__global__ __launch_bounds__(256)
void gemm_cheb(const float* __restrict__ T0c, const float* __restrict__ T1c,
               const float* __restrict__ T2c, const float* __restrict__ T3c,
               const float* __restrict__ bnp, const float* __restrict__ W,
               const float* __restrict__ bias, float* __restrict__ out,
               float* __restrict__ stats, int N) {
    __shared__ float As[8][132];
    __shared__ float Bs[8][132];
    __shared__ float s_sum[128];
    __shared__ float s_sq[128];
    int tid = threadIdx.x;
    int tx = tid & 15, ty = tid >> 4;
    int row0 = blockIdx.x * 128;
    float acc[8][8] = {};
    const float* Ts[4] = {T0c, T1c, T2c, T3c};
    if (STATS && tid < 128) { s_sum[tid] = 0.f; s_sq[tid] = 0.f; }

    int ar = tid >> 1;            // A row 0..127
    int ac = (tid & 1) * 4;       // A k offset 0 or 4
    int br = tid >> 5;            // B k row 0..7
    int bc = (tid * 4) & 127;     // B col

    bool arow_ok = (row0 + ar) < N;

    for (int sel = 0; sel < 4; ++sel) {
        const float* __restrict__ Tp = Ts[sel];
        const float* __restrict__ Wp = W + sel * 16384;
        for (int kt = 0; kt < 16; ++kt) {
            int k0 = kt * 8;
            __syncthreads();
            float4 av = make_float4(0.f, 0.f, 0.f, 0.f);
            if (arow_ok) {
                av = *(const float4*)(Tp + (size_t)(row0 + ar) * HDIM + k0 + ac);
                if (sel == 0) {
                    float4 s4 = *(const float4*)(bnp + k0 + ac);
                    float4 h4 = *(const float4*)(bnp + 128 + k0 + ac);
                    av.x = av.x * s4.x + h4.x; av.y = av.y * s4.y + h4.y;
                    av.z = av.z * s4.z + h4.z; av.w = av.w * s4.w + h4.w;
                }
            }
            As[ac + 0][ar] = av.x; As[ac + 1][ar] = av.y;
            As[ac + 2][ar] = av.z; As[ac + 3][ar] = av.w;
            float4 bv = *(const float4*)(Wp + (size_t)(k0 + br) * HDIM + bc);
            *(float4*)&Bs[br][bc] = bv;
            __syncthreads();
#pragma unroll
            for (int kk = 0; kk < 8; ++kk) {
                float a[8], b[8];
                *(float4*)&a[0] = *(const float4*)&As[kk][ty * 8];
                *(float4*)&a[4] = *(const float4*)&As[kk][ty * 8 + 4];
                *(float4*)&b[0] = *(const float4*)&Bs[kk][tx * 8];
                *(float4*)&b[4] = *(const float4*)&Bs[kk][tx * 8 + 4];
#pragma unroll
                for (int i = 0; i < 8; ++i)
#pragma unroll
                    for (int j = 0; j < 8; ++j) acc[i][j] += a[i] * b[j];
            }
        }
    }

    float bj[8];
#pragma unroll
    for (int j = 0; j < 8; ++j) bj[j] = bias[tx * 8 + j];
    float csum[8] = {}, csq[8] = {};
#pragma unroll
    for (int i = 0; i < 8; ++i) {
        int r = row0 + ty * 8 + i;
        if (r < N) {
            float vv[8];
#pragma unroll
            for (int j = 0; j < 8; ++j) {
                float v = acc[i][j] + bj[j];
                if (ACT == 1) v = v >= 0.f ? v : 0.01f * v;
                else if (ACT == 2) v = fmaxf(v, 0.f);
                vv[j] = v;
                if (STATS) { csum[j] += v; csq[j] += v * v; }
            }
            *(float4*)(out + (size_t)r * HDIM + tx * 8) = *(float4*)&vv[0];
            *(float4*)(out + (size_t)r * HDIM + tx * 8 + 4) = *(float4*)&vv[4];
        }
    }
    if (STATS) {
#pragma unroll
        for (int j = 0; j < 8; ++j) {
            atomicAdd(&s_sum[tx * 8 + j], csum[j]);
            atomicAdd(&s_sq[tx * 8 + j], csq[j]);
        }
        __syncthreads();
        if (tid < 128) {
            atomicAdd(&stats[tid], s_sum[tid]);
            atomicAdd(&stats[128 + tid], s_sq[tid]);
        }
    }
}

// ---------------- layer-1 (input dim 3) fused GEMM, grid-stride ----------------
__global__ __launch_bounds__(256)
void gemm1_kernel(const float* __restrict__ x, const float* __restrict__ t1,
                  const float* __restrict__ t2, const float* __restrict__ t3,
                  const float* __restrict__ W1, const float* __restrict__ b1,
                  float* __restrict__ out, float* __restrict__ stats, int N) {
    __shared__ float s_sum[128];
    __shared__ float s_sq[128];
    int tid = threadIdx.x;
    int c = tid & 127;
    if (tid < 128) { s_sum[tid] = 0.f; s_sq[tid] = 0.f; }
    __syncthreads();
    float wreg[12];
#pragma unroll
    for (int i = 0; i < 12; ++i) wreg[i] = W1[i * 128 + c];
    float bias = b1[c];
    const float* Ts[4] = {x, t1, t2, t3};
    float lsum = 0.f, lsq = 0.f;
    for (int row = blockIdx.x * 2 + (tid >> 7); row < N; row += gridDim.x * 2) {
        float v = bias;
#pragma unroll
        for (int k = 0; k < 4; ++k) {
            const float* t = Ts[k];
#pragma unroll
            for (int d = 0; d < 3; ++d)
                v += t[row * 3 + d] * wreg[k * 3 + d];
        }
        v = v >= 0.f ? v : 0.01f * v;   // leaky_relu
        out[(size_t)row * HDIM + c] = v;
        lsum += v; lsq += v * v;
    }
    atomicAdd(&s_sum[c], lsum);
    atomicAdd(&s_sq[c], lsq);
    __syncthreads();
    if (tid < 128) {
        atomicAdd(&stats[tid], s_sum[tid]);
        atomicAdd(&stats[128 + tid], s_sq[tid]);
    }
}

// ---------------- BN finalize: stats -> (scale, shift) ----------------
__global__ void bnfin_kernel(const float* __restrict__ stats, const float* __restrict__ g,
                             const float* __restrict__ be, float* __restrict__ bnp, float invN) {
    int c = threadIdx.x;  // 128 threads
    float m = stats[c] * invN;
    float v = stats[128 + c] * invN - m * m;
    float sc = g[c] * rsqrtf(v + 1e-5f);
    bnp[c] = sc;
    bnp[128 + c] = be[c] - m * sc;
}

// ---------------- final: L2-normalize row + project to 3 ----------------
__global__ void final_kernel(const float* __restrict__ Z, const float* __restrict__ Wm,
                             const float* __restrict__ bm, float* __restrict__ out, int N) {
    int gid = blockIdx.x * blockDim.x + threadIdx.x;
    int node = gid >> 6;
    int lane = threadIdx.x & 63;
    if (node >= N) return;
    const float* z = Z + (size_t)node * HDIM;
    float z0 = z[lane], z1 = z[lane + 64];
    float sq = z0 * z0 + z1 * z1;
    float d0 = z0 * Wm[lane * 3 + 0] + z1 * Wm[(lane + 64) * 3 + 0];
    float d1 = z0 * Wm[lane * 3 + 1] + z1 * Wm[(lane + 64) * 3 + 1];
    float d2 = z0 * Wm[lane * 3 + 2] + z1 * Wm[(lane + 64) * 3 + 2];
#pragma unroll
    for (int off = 32; off > 0; off >>= 1) {
        sq += __shfl_down(sq, off);
        d0 += __shfl_down(d0, off);
        d1 += __shfl_down(d1, off);
        d2 += __shfl_down(d2, off);
    }
    if (lane == 0) {
        float inv = 1.f / fmaxf(sqrtf(sq), 1e-12f);
        out[node * 3 + 0] = d0 * inv + bm[0];
        out[node * 3 + 1] = d1 * inv + bm[1];
        out[node * 3 + 2] = d2 * inv + bm[2];
    }
}

// ---------------- host ----------------

extern "C" void kernel_launch(void* const* d_in, const int* in_sizes, int n_in,
                              void* d_out, int out_size, void* d_ws, size_t ws_size,
                              hipStream_t stream) {
    const float* x  = (const float*)d_in[0];
    const int*   ei = (const int*)d_in[1];
    const float* W1 = (const float*)d_in[2];
    const float* b1 = (const float*)d_in[3];
    const float* W2 = (const float*)d_in[4];
    const float* b2 = (const float*)d_in[5];
    const float* W3 = (const float*)d_in[6];
    const float* b3 = (const float*)d_in[7];
    const float* W4 = (const float*)d_in[8];
    const float* b4 = (const float*)d_in[9];
    const float* g1 = (const float*)d_in[10];
    const float* be1 = (const float*)d_in[11];
    const float* g2 = (const float*)d_in[12];
    const float* be2 = (const float*)d_in[13];
    const float* g3 = (const float*)d_in[14];
    const float* be3 = (const float*)d_in[15];
    const float* Wm = (const float*)d_in[16];
    const float* bm = (const float*)d_in[17];
    float* out = (float*)d_out;

    const int N = in_sizes[0] / 3;
    const int E = in_sizes[1] / 2;
    const size_t NH = (size_t)N * HDIM;
    const int* src = ei;
    const int* dst = ei + E;

    // ---- workspace layout ----
    char* base = (char*)d_ws;
    int* degS   = (int*)base;            base += (size_t)N * 4;
    int* degD   = (int*)base;            base += (size_t)N * 4;
    int* cursor = (int*)base;            base += (size_t)N * 4;
    int* rp     = (int*)base;            base += (size_t)(N + 2) * 4;
    int2* ev    = (int2*)base;           base += (size_t)E * 8;
    float* dinv = (float*)base;          base += (size_t)N * 4;
    float* Za   = (float*)base;          base += NH * 4;
    float* Zb   = (float*)base;          base += NH * 4;
    float* T1   = (float*)base;          base += NH * 4;
    float* T2   = (float*)base;          base += NH * 4;
    float* T3   = (float*)base;          base += NH * 4;
    float* x1   = (float*)base;          base += (size_t)N * 3 * 4;
    float* x2   = (float*)base;          base += (size_t)N * 3 * 4;
    float* x3   = (float*)base;          base += (size_t)N * 3 * 4;
    float* stats = (float*)base;         base += 256 * 4;
    float* bnp1  = (float*)base;         base += 256 * 4;
    float* bnp2  = (float*)base;         base += 256 * 4;
    float* bnp3  = (float*)base;         base += 256 * 4;

    const int EB = (E + 255) / 256;
    const int NB = (N + 255) / 256;
    const int GB = (N + 127) / 128;       // gemm row tiles (128 rows)
    const int PB = (N + 3) / 4;           // pull128 blocks (4 nodes/block)
    const float invN = 1.f / (float)N;

    // --- CSR build + edge weights ---
    hipMemsetAsync(degS, 0, (size_t)N * 3 * 4, stream);   // degS, degD, cursor
    degs_kernel<<<EB, 256, 0, stream>>>(src, dst, degS, degD, E);
    dinv_kernel<<<NB, 256, 0, stream>>>(degS, dinv, N);
    scan_kernel<<<1, 1024, 0, stream>>>(degD, rp, N);
    scatter_kernel<<<EB, 256, 0, stream>>>(src, dst, dinv, rp, cursor, ev, E);

    // --- layer 1 (dim 3) -> Za, bnp1 ---
    pull3<<<NB, 256, 0, stream>>>(x,  nullptr, rp, ev, x1, 1.f, N);
    pull3<<<NB, 256, 0, stream>>>(x1, x,       rp, ev, x2, 2.f, N);
    pull3<<<NB, 256, 0, stream>>>(x2, x1,      rp, ev, x3, 2.f, N);
    hipMemsetAsync(stats, 0, 256 * 4, stream);
    gemm1_kernel<<<512, 256, 0, stream>>>(x, x1, x2, x3, W1, b1, Za, stats, N);
    bnfin_kernel<<<1, 128, 0, stream>>>(stats, g1, be1, bnp1, invN);

    // --- layer 2 (leaky + BN): input BN(Za,bnp1) -> Zb, bnp2 ---
    pull128<1, 0><<<PB, 256, 0, stream>>>(Za, rp, ev, nullptr, bnp1, T1, 1.f, N);
    pull128<0, 1><<<PB, 256, 0, stream>>>(T1, rp, ev, Za, bnp1, T2, 2.f, N);
    pull128<0, 0><<<PB, 256, 0, stream>>>(T2, rp, ev, T1, nullptr, T3, 2.f, N);
    hipMemsetAsync(stats, 0, 256 * 4, stream);
    gemm_cheb<1, 1><<<GB, 256, 0, stream>>>(Za, T1, T2, T3, bnp1, W2, b2, Zb, stats, N);
    bnfin_kernel<<<1, 128, 0, stream>>>(stats, g2, be2, bnp2, invN);

    // --- layer 3 (relu + BN): input BN(Zb,bnp2) -> Za, bnp3 ---
    pull128<1, 0><<<PB, 256, 0, stream>>>(Zb, rp, ev, nullptr, bnp2, T1, 1.f, N);
    pull128<0, 1><<<PB, 256, 0, stream>>>(T1, rp, ev, Zb, bnp2, T2, 2.f, N);
    pull128<0, 0><<<PB, 256, 0, stream>>>(T2, rp, ev, T1, nullptr, T3, 2.f, N);
    hipMemsetAsync(stats, 0, 256 * 4, stream);
    gemm_cheb<2, 1><<<GB, 256, 0, stream>>>(Zb, T1, T2, T3, bnp2, W3, b3, Za, stats, N);
    bnfin_kernel<<<1, 128, 0, stream>>>(stats, g3, be3, bnp3, invN);

    // --- layer 4 (no act/BN): input BN(Za,bnp3) -> Zb ---
    pull128<1, 0><<<PB, 256, 0, stream>>>(Za, rp, ev, nullptr, bnp3, T1, 1.f, N);
    pull128<0, 1><<<PB, 256, 0, stream>>>(T1, rp, ev, Za, bnp3, T2, 2.f, N);
    pull128<0, 0><<<PB, 256, 0, stream>>>(T2, rp, ev, T1, nullptr, T3, 2.f, N);
    gemm_cheb<0, 0><<<GB, 256, 0, stream>>>(Za, T1, T2, T3, bnp3, W4, b4, Zb, nullptr, N);

    // --- normalize + project ---
    final_kernel<<<(N * 64 + 255) / 256, 256, 0, stream>>>(Zb, Wm, bm, out, N);
}

// Round 5
// 1093.180 us; speedup vs baseline: 4.3022x; 1.2545x over previous
//
#include <hip/hip_runtime.h>
#include <hip/hip_fp16.h>
#include <math.h>

#define HDIM 128

struct alignas(8) half4 { __half2 lo, hi; };

__device__ __forceinline__ float4 h4_to_f4(half4 h) {
    float2 a = __half22float2(h.lo), b = __half22float2(h.hi);
    return make_float4(a.x, a.y, b.x, b.y);
}
__device__ __forceinline__ half4 f4_to_h4(float4 f) {
    half4 h;
    h.lo = __float22half2_rn(make_float2(f.x, f.y));
    h.hi = __float22half2_rn(make_float2(f.z, f.w));
    return h;
}

// ---------------- degree / CSR build ----------------

__global__ void degs_kernel(const int* __restrict__ src, const int* __restrict__ dst,
                            int* __restrict__ degS, int* __restrict__ degD, int E) {
    int e = blockIdx.x * blockDim.x + threadIdx.x;
    if (e < E) {
        atomicAdd(&degS[src[e]], 1);
        atomicAdd(&degD[dst[e]], 1);
    }
}

__global__ void dinv_kernel(const int* __restrict__ degS, float* __restrict__ dinv, int N) {
    int i = blockIdx.x * blockDim.x + threadIdx.x;
    if (i < N) { int d = degS[i]; dinv[i] = d > 0 ? rsqrtf((float)d) : 0.f; }
}

// single-block exclusive scan of degD -> rp[0..N], rp[N] = E
__global__ __launch_bounds__(1024)
void scan_kernel(const int* __restrict__ deg, int* __restrict__ rp, int N) {
    __shared__ int part[1024];
    int tid = threadIdx.x;
    int chunk = (N + 1023) / 1024;
    int start = tid * chunk;
    int end = start + chunk; if (end > N) end = N;
    int s = 0;
    for (int i = start; i < end; ++i) s += deg[i];
    part[tid] = s;
    __syncthreads();
    for (int off = 1; off < 1024; off <<= 1) {
        int v = (tid >= off) ? part[tid - off] : 0;
        __syncthreads();
        part[tid] += v;
        __syncthreads();
    }
    int run = (tid == 0) ? 0 : part[tid - 1];
    for (int i = start; i < end; ++i) { rp[i] = run; run += deg[i]; }
    if (start < N && end == N) rp[N] = run;
}

__global__ void scatter_kernel(const int* __restrict__ src, const int* __restrict__ dst,
                               const float* __restrict__ dinv, const int* __restrict__ rp,
                               int* __restrict__ cursor, int2* __restrict__ ev, int E) {
    int e = blockIdx.x * blockDim.x + threadIdx.x;
    if (e >= E) return;
    int s = src[e], d = dst[e];
    float w = -dinv[s] * dinv[d];
    int pos = atomicAdd(&cursor[d], 1);
    ev[rp[d] + pos] = make_int2(s, __float_as_int(w));
}

// ---------------- pull propagation (fp16 tables, fp32 accumulate) ----------
// out[i] = alpha * sum_e w * g(t[src]) - p(prev[i])
//   GBN: g applies BN (scale/shift from bnp) to gathered rows; prev unused
//   else prev != null; PBN: p applies BN to prev
template <int GBN, int PBN>
__global__ __launch_bounds__(256)
void pull128(const __half* __restrict__ t, const int* __restrict__ rp,
             const int2* __restrict__ ev, const __half* __restrict__ prev,
             const float* __restrict__ bnp, __half* __restrict__ outp,
             float alpha, int N) {
    int node = blockIdx.x * 4 + (threadIdx.x >> 6);
    if (node >= N) return;
    int lane = threadIdx.x & 63;
    int c4 = (lane & 31) * 4;     // channel group (4 channels, 8 B fp16)
    int epar = lane >> 5;         // edge parity for this half-wave

    float4 sc = make_float4(1.f, 1.f, 1.f, 1.f);
    float4 sh = make_float4(0.f, 0.f, 0.f, 0.f);
    if (GBN || PBN) {
        sc = *(const float4*)(bnp + c4);
        sh = *(const float4*)(bnp + 128 + c4);
    }

    int b = rp[node], e = rp[node + 1];
    float4 a0 = {0,0,0,0}, a1 = {0,0,0,0}, a2 = {0,0,0,0}, a3 = {0,0,0,0};

    int j = b;
    for (; j + 8 <= e; j += 8) {
        int2 s0 = ev[j + 0 + epar];
        int2 s1 = ev[j + 2 + epar];
        int2 s2 = ev[j + 4 + epar];
        int2 s3 = ev[j + 6 + epar];
        float4 r0 = h4_to_f4(*(const half4*)(t + (size_t)s0.x * HDIM + c4));
        float4 r1 = h4_to_f4(*(const half4*)(t + (size_t)s1.x * HDIM + c4));
        float4 r2 = h4_to_f4(*(const half4*)(t + (size_t)s2.x * HDIM + c4));
        float4 r3 = h4_to_f4(*(const half4*)(t + (size_t)s3.x * HDIM + c4));
        float w0 = __int_as_float(s0.y), w1 = __int_as_float(s1.y);
        float w2 = __int_as_float(s2.y), w3 = __int_as_float(s3.y);
        if (GBN) {
            r0.x = r0.x * sc.x + sh.x; r0.y = r0.y * sc.y + sh.y; r0.z = r0.z * sc.z + sh.z; r0.w = r0.w * sc.w + sh.w;
            r1.x = r1.x * sc.x + sh.x; r1.y = r1.y * sc.y + sh.y; r1.z = r1.z * sc.z + sh.z; r1.w = r1.w * sc.w + sh.w;
            r2.x = r2.x * sc.x + sh.x; r2.y = r2.y * sc.y + sh.y; r2.z = r2.z * sc.z + sh.z; r2.w = r2.w * sc.w + sh.w;
            r3.x = r3.x * sc.x + sh.x; r3.y = r3.y * sc.y + sh.y; r3.z = r3.z * sc.z + sh.z; r3.w = r3.w * sc.w + sh.w;
        }
        a0.x += w0 * r0.x; a0.y += w0 * r0.y; a0.z += w0 * r0.z; a0.w += w0 * r0.w;
        a1.x += w1 * r1.x; a1.y += w1 * r1.y; a1.z += w1 * r1.z; a1.w += w1 * r1.w;
        a2.x += w2 * r2.x; a2.y += w2 * r2.y; a2.z += w2 * r2.z; a2.w += w2 * r2.w;
        a3.x += w3 * r3.x; a3.y += w3 * r3.y; a3.z += w3 * r3.z; a3.w += w3 * r3.w;
    }
    for (; j + 2 <= e; j += 2) {
        int2 s0 = ev[j + epar];
        float w0 = __int_as_float(s0.y);
        float4 r0 = h4_to_f4(*(const half4*)(t + (size_t)s0.x * HDIM + c4));
        if (GBN) {
            r0.x = r0.x * sc.x + sh.x; r0.y = r0.y * sc.y + sh.y; r0.z = r0.z * sc.z + sh.z; r0.w = r0.w * sc.w + sh.w;
        }
        a0.x += w0 * r0.x; a0.y += w0 * r0.y; a0.z += w0 * r0.z; a0.w += w0 * r0.w;
    }
    if (j < e && epar == 0) {   // odd leftover handled by low half-wave
        int2 s0 = ev[j];
        float w0 = __int_as_float(s0.y);
        float4 r0 = h4_to_f4(*(const half4*)(t + (size_t)s0.x * HDIM + c4));
        if (GBN) {
            r0.x = r0.x * sc.x + sh.x; r0.y = r0.y * sc.y + sh.y; r0.z = r0.z * sc.z + sh.z; r0.w = r0.w * sc.w + sh.w;
        }
        a1.x += w0 * r0.x; a1.y += w0 * r0.y; a1.z += w0 * r0.z; a1.w += w0 * r0.w;
    }

    float4 s4;
    s4.x = (a0.x + a1.x) + (a2.x + a3.x);
    s4.y = (a0.y + a1.y) + (a2.y + a3.y);
    s4.z = (a0.z + a1.z) + (a2.z + a3.z);
    s4.w = (a0.w + a1.w) + (a2.w + a3.w);
    s4.x += __shfl_xor(s4.x, 32);
    s4.y += __shfl_xor(s4.y, 32);
    s4.z += __shfl_xor(s4.z, 32);
    s4.w += __shfl_xor(s4.w, 32);

    if (lane < 32) {
        size_t o = (size_t)node * HDIM + c4;
        float4 r;
        r.x = alpha * s4.x; r.y = alpha * s4.y; r.z = alpha * s4.z; r.w = alpha * s4.w;
        if (!GBN) {
            float4 pv = h4_to_f4(*(const half4*)(prev + o));
            if (PBN) {
                pv.x = pv.x * sc.x + sh.x; pv.y = pv.y * sc.y + sh.y;
                pv.z = pv.z * sc.z + sh.z; pv.w = pv.w * sc.w + sh.w;
            }
            r.x -= pv.x; r.y -= pv.y; r.z -= pv.z; r.w -= pv.w;
        }
        *(half4*)(outp + o) = f4_to_h4(r);
    }
}

__global__ void pull3(const float* __restrict__ t, const float* __restrict__ prev,
                      const int* __restrict__ rp, const int2* __restrict__ ev,
                      float* __restrict__ outp, float alpha, int N) {
    int node = blockIdx.x * blockDim.x + threadIdx.x;
    if (node >= N) return;
    int b = rp[node], e = rp[node + 1];
    float a0 = 0.f, a1 = 0.f, a2 = 0.f;
    for (int j = b; j < e; ++j) {
        int2 sw = ev[j];
        float w = __int_as_float(sw.y);
        const float* r = t + (size_t)sw.x * 3;
        a0 += w * r[0]; a1 += w * r[1]; a2 += w * r[2];
    }
    float r0 = alpha * a0, r1 = alpha * a1, r2 = alpha * a2;
    if (prev) {
        r0 -= prev[node * 3 + 0];
        r1 -= prev[node * 3 + 1];
        r2 -= prev[node * 3 + 2];
    }
    outp[node * 3 + 0] = r0;
    outp[node * 3 + 1] = r1;
    outp[node * 3 + 2] = r2;
}

// ---------------- fused Cheb GEMM ------------------------------------------
// Z = BN(T0)@W0 + T1@W1 + T2@W2 + T3@W3 + b, act, BN-stats.
// 64x128 tile (782 blocks -> ~3 blocks/CU), BK=8, single LDS buffer,
// fp16 A-tiles converted to fp32 in LDS, fp32 weights, fp32 accumulate.
// OUTH=1: fp16 output (inter-layer); OUTH=0: fp32 output (last layer).
template <int ACT, int STATS, int OUTH>
__global__ __launch_bounds__(256)
void gemm_cheb(const __half* __restrict__ T0c, const __half* __restrict__ T1c,
               const __half* __restrict__ T2c, const __half* __restrict__ T3c,
               const float* __restrict__ bnp, const float* __restrict__ W,
               const float* __restrict__ bias, __half* __restrict__ outh,
               float* __restrict__ outf, float* __restrict__ stats, int N) {
    __shared__ float As[8][68];
    __shared__ float Bs[8][132];
    __shared__ float s_sum[128];
    __shared__ float s_sq[128];
    int tid = threadIdx.x;
    int tx = tid & 31;            // col group: cols tx*4..+3
    int rg = tid >> 5;            // row group: rows rg*8..+7
    int row0 = blockIdx.x * 64;
    float acc[8][4] = {};
    const __half* Ts[4] = {T0c, T1c, T2c, T3c};
    if (STATS && tid < 128) { s_sum[tid] = 0.f; s_sq[tid] = 0.f; }

    int arow = tid >> 2;          // A row 0..63
    int akc = (tid & 3) * 2;      // A k offset 0/2/4/6
    int bkr = tid >> 5;           // B k row 0..7
    int bcc = (tid & 31) * 4;     // B col

    bool arow_ok = (row0 + arow) < N;

    for (int sel = 0; sel < 4; ++sel) {
        const __half* __restrict__ Tp = Ts[sel];
        const float* __restrict__ Wp = W + sel * 16384;
        for (int kt = 0; kt < 16; ++kt) {
            int k0 = kt * 8;
            __syncthreads();
            float2 af = make_float2(0.f, 0.f);
            if (arow_ok) {
                __half2 ah = *(const __half2*)(Tp + (size_t)(row0 + arow) * HDIM + k0 + akc);
                af = __half22float2(ah);
                if (sel == 0) {
                    af.x = af.x * bnp[k0 + akc] + bnp[128 + k0 + akc];
                    af.y = af.y * bnp[k0 + akc + 1] + bnp[128 + k0 + akc + 1];
                }
            }
            As[akc + 0][arow] = af.x;
            As[akc + 1][arow] = af.y;
            float4 bv = *(const float4*)(Wp + (size_t)(k0 + bkr) * HDIM + bcc);
            *(float4*)&Bs[bkr][bcc] = bv;
            __syncthreads();
#pragma unroll
            for (int k = 0; k < 8; ++k) {
                float a[8], b[4];
                *(float4*)&a[0] = *(const float4*)&As[k][rg * 8];
                *(float4*)&a[4] = *(const float4*)&As[k][rg * 8 + 4];
                *(float4*)&b[0] = *(const float4*)&Bs[k][tx * 4];
#pragma unroll
                for (int i = 0; i < 8; ++i)
#pragma unroll
                    for (int j = 0; j < 4; ++j) acc[i][j] += a[i] * b[j];
            }
        }
    }

    float bj[4];
#pragma unroll
    for (int j = 0; j < 4; ++j) bj[j] = bias[tx * 4 + j];
    float csum[4] = {}, csq[4] = {};
#pragma unroll
    for (int i = 0; i < 8; ++i) {
        int r = row0 + rg * 8 + i;
        if (r < N) {
            float4 vv;
            float* vp = (float*)&vv;
#pragma unroll
            for (int j = 0; j < 4; ++j) {
                float v = acc[i][j] + bj[j];
                if (ACT == 1) v = v >= 0.f ? v : 0.01f * v;
                else if (ACT == 2) v = fmaxf(v, 0.f);
                vp[j] = v;
                if (STATS) { csum[j] += v; csq[j] += v * v; }
            }
            if (OUTH) *(half4*)(outh + (size_t)r * HDIM + tx * 4) = f4_to_h4(vv);
            else      *(float4*)(outf + (size_t)r * HDIM + tx * 4) = vv;
        }
    }
    if (STATS) {
#pragma unroll
        for (int j = 0; j < 4; ++j) {
            atomicAdd(&s_sum[tx * 4 + j], csum[j]);
            atomicAdd(&s_sq[tx * 4 + j], csq[j]);
        }
        __syncthreads();
        if (tid < 128) {
            atomicAdd(&stats[tid], s_sum[tid]);
            atomicAdd(&stats[128 + tid], s_sq[tid]);
        }
    }
}

// ---------------- layer-1 (input dim 3) fused GEMM, grid-stride ----------------
__global__ __launch_bounds__(256)
void gemm1_kernel(const float* __restrict__ x, const float* __restrict__ t1,
                  const float* __restrict__ t2, const float* __restrict__ t3,
                  const float* __restrict__ W1, const float* __restrict__ b1,
                  __half* __restrict__ out, float* __restrict__ stats, int N) {
    __shared__ float s_sum[128];
    __shared__ float s_sq[128];
    int tid = threadIdx.x;
    int c = tid & 127;
    if (tid < 128) { s_sum[tid] = 0.f; s_sq[tid] = 0.f; }
    __syncthreads();
    float wreg[12];
#pragma unroll
    for (int i = 0; i < 12; ++i) wreg[i] = W1[i * 128 + c];
    float bias = b1[c];
    const float* Ts[4] = {x, t1, t2, t3};
    float lsum = 0.f, lsq = 0.f;
    for (int row = blockIdx.x * 2 + (tid >> 7); row < N; row += gridDim.x * 2) {
        float v = bias;
#pragma unroll
        for (int k = 0; k < 4; ++k) {
            const float* t = Ts[k];
#pragma unroll
            for (int d = 0; d < 3; ++d)
                v += t[row * 3 + d] * wreg[k * 3 + d];
        }
        v = v >= 0.f ? v : 0.01f * v;   // leaky_relu
        out[(size_t)row * HDIM + c] = __float2half(v);
        lsum += v; lsq += v * v;
    }
    atomicAdd(&s_sum[c], lsum);
    atomicAdd(&s_sq[c], lsq);
    __syncthreads();
    if (tid < 128) {
        atomicAdd(&stats[tid], s_sum[tid]);
        atomicAdd(&stats[128 + tid], s_sq[tid]);
    }
}

// ---------------- BN finalize: stats -> (scale, shift) ----------------
__global__ void bnfin_kernel(const float* __restrict__ stats, const float* __restrict__ g,
                             const float* __restrict__ be, float* __restrict__ bnp, float invN) {
    int c = threadIdx.x;  // 128 threads
    float m = stats[c] * invN;
    float v = stats[128 + c] * invN - m * m;
    float sc = g[c] * rsqrtf(v + 1e-5f);
    bnp[c] = sc;
    bnp[128 + c] = be[c] - m * sc;
}

// ---------------- final: L2-normalize row + project to 3 ----------------
__global__ void final_kernel(const float* __restrict__ Z, const float* __restrict__ Wm,
                             const float* __restrict__ bm, float* __restrict__ out, int N) {
    int gid = blockIdx.x * blockDim.x + threadIdx.x;
    int node = gid >> 6;
    int lane = threadIdx.x & 63;
    if (node >= N) return;
    const float* z = Z + (size_t)node * HDIM;
    float z0 = z[lane], z1 = z[lane + 64];
    float sq = z0 * z0 + z1 * z1;
    float d0 = z0 * Wm[lane * 3 + 0] + z1 * Wm[(lane + 64) * 3 + 0];
    float d1 = z0 * Wm[lane * 3 + 1] + z1 * Wm[(lane + 64) * 3 + 1];
    float d2 = z0 * Wm[lane * 3 + 2] + z1 * Wm[(lane + 64) * 3 + 2];
#pragma unroll
    for (int off = 32; off > 0; off >>= 1) {
        sq += __shfl_down(sq, off);
        d0 += __shfl_down(d0, off);
        d1 += __shfl_down(d1, off);
        d2 += __shfl_down(d2, off);
    }
    if (lane == 0) {
        float inv = 1.f / fmaxf(sqrtf(sq), 1e-12f);
        out[node * 3 + 0] = d0 * inv + bm[0];
        out[node * 3 + 1] = d1 * inv + bm[1];
        out[node * 3 + 2] = d2 * inv + bm[2];
    }
}

// ---------------- host ----------------

extern "C" void kernel_launch(void* const* d_in, const int* in_sizes, int n_in,
                              void* d_out, int out_size, void* d_ws, size_t ws_size,
                              hipStream_t stream) {
    const float* x  = (const float*)d_in[0];
    const int*   ei = (const int*)d_in[1];
    const float* W1 = (const float*)d_in[2];
    const float* b1 = (const float*)d_in[3];
    const float* W2 = (const float*)d_in[4];
    const float* b2 = (const float*)d_in[5];
    const float* W3 = (const float*)d_in[6];
    const float* b3 = (const float*)d_in[7];
    const float* W4 = (const float*)d_in[8];
    const float* b4 = (const float*)d_in[9];
    const float* g1 = (const float*)d_in[10];
    const float* be1 = (const float*)d_in[11];
    const float* g2 = (const float*)d_in[12];
    const float* be2 = (const float*)d_in[13];
    const float* g3 = (const float*)d_in[14];
    const float* be3 = (const float*)d_in[15];
    const float* Wm = (const float*)d_in[16];
    const float* bm = (const float*)d_in[17];
    float* out = (float*)d_out;

    const int N = in_sizes[0] / 3;
    const int E = in_sizes[1] / 2;
    const size_t NH = (size_t)N * HDIM;
    const int* src = ei;
    const int* dst = ei + E;

    // ---- workspace layout ----
    char* base = (char*)d_ws;
    int* degS   = (int*)base;            base += (size_t)N * 4;
    int* degD   = (int*)base;            base += (size_t)N * 4;
    int* cursor = (int*)base;            base += (size_t)N * 4;
    int* rp     = (int*)base;            base += (size_t)(N + 2) * 4;
    int2* ev    = (int2*)base;           base += (size_t)E * 8;
    float* dinv = (float*)base;          base += (size_t)N * 4;
    __half* Za  = (__half*)base;         base += NH * 2;
    __half* Zb  = (__half*)base;         base += NH * 2;
    __half* T1  = (__half*)base;         base += NH * 2;
    __half* T2  = (__half*)base;         base += NH * 2;
    __half* T3  = (__half*)base;         base += NH * 2;
    float* Zf   = (float*)base;          base += NH * 4;   // layer-4 out, fp32
    float* x1   = (float*)base;          base += (size_t)N * 3 * 4;
    float* x2   = (float*)base;          base += (size_t)N * 3 * 4;
    float* x3   = (float*)base;          base += (size_t)N * 3 * 4;
    float* stats = (float*)base;         base += 256 * 4;
    float* bnp1  = (float*)base;         base += 256 * 4;
    float* bnp2  = (float*)base;         base += 256 * 4;
    float* bnp3  = (float*)base;         base += 256 * 4;

    const int EB = (E + 255) / 256;
    const int NB = (N + 255) / 256;
    const int GB = (N + 63) / 64;         // gemm row tiles (64 rows)
    const int PB = (N + 3) / 4;           // pull128 blocks (4 nodes/block)
    const float invN = 1.f / (float)N;

    // --- CSR build + edge weights ---
    hipMemsetAsync(degS, 0, (size_t)N * 3 * 4, stream);   // degS, degD, cursor
    degs_kernel<<<EB, 256, 0, stream>>>(src, dst, degS, degD, E);
    dinv_kernel<<<NB, 256, 0, stream>>>(degS, dinv, N);
    scan_kernel<<<1, 1024, 0, stream>>>(degD, rp, N);
    scatter_kernel<<<EB, 256, 0, stream>>>(src, dst, dinv, rp, cursor, ev, E);

    // --- layer 1 (dim 3) -> Za (fp16), bnp1 ---
    pull3<<<NB, 256, 0, stream>>>(x,  nullptr, rp, ev, x1, 1.f, N);
    pull3<<<NB, 256, 0, stream>>>(x1, x,       rp, ev, x2, 2.f, N);
    pull3<<<NB, 256, 0, stream>>>(x2, x1,      rp, ev, x3, 2.f, N);
    hipMemsetAsync(stats, 0, 256 * 4, stream);
    gemm1_kernel<<<512, 256, 0, stream>>>(x, x1, x2, x3, W1, b1, Za, stats, N);
    bnfin_kernel<<<1, 128, 0, stream>>>(stats, g1, be1, bnp1, invN);

    // --- layer 2 (leaky + BN): input BN(Za,bnp1) -> Zb, bnp2 ---
    pull128<1, 0><<<PB, 256, 0, stream>>>(Za, rp, ev, nullptr, bnp1, T1, 1.f, N);
    pull128<0, 1><<<PB, 256, 0, stream>>>(T1, rp, ev, Za, bnp1, T2, 2.f, N);
    pull128<0, 0><<<PB, 256, 0, stream>>>(T2, rp, ev, T1, nullptr, T3, 2.f, N);
    hipMemsetAsync(stats, 0, 256 * 4, stream);
    gemm_cheb<1, 1, 1><<<GB, 256, 0, stream>>>(Za, T1, T2, T3, bnp1, W2, b2, Zb, nullptr, stats, N);
    bnfin_kernel<<<1, 128, 0, stream>>>(stats, g2, be2, bnp2, invN);

    // --- layer 3 (relu + BN): input BN(Zb,bnp2) -> Za, bnp3 ---
    pull128<1, 0><<<PB, 256, 0, stream>>>(Zb, rp, ev, nullptr, bnp2, T1, 1.f, N);
    pull128<0, 1><<<PB, 256, 0, stream>>>(T1, rp, ev, Zb, bnp2, T2, 2.f, N);
    pull128<0, 0><<<PB, 256, 0, stream>>>(T2, rp, ev, T1, nullptr, T3, 2.f, N);
    hipMemsetAsync(stats, 0, 256 * 4, stream);
    gemm_cheb<2, 1, 1><<<GB, 256, 0, stream>>>(Zb, T1, T2, T3, bnp2, W3, b3, Za, nullptr, stats, N);
    bnfin_kernel<<<1, 128, 0, stream>>>(stats, g3, be3, bnp3, invN);

    // --- layer 4 (no act/BN): input BN(Za,bnp3) -> Zf (fp32) ---
    pull128<1, 0><<<PB, 256, 0, stream>>>(Za, rp, ev, nullptr, bnp3, T1, 1.f, N);
    pull128<0, 1><<<PB, 256, 0, stream>>>(T1, rp, ev, Za, bnp3, T2, 2.f, N);
    pull128<0, 0><<<PB, 256, 0, stream>>>(T2, rp, ev, T1, nullptr, T3, 2.f, N);
    gemm_cheb<0, 0, 0><<<GB, 256, 0, stream>>>(Za, T1, T2, T3, bnp3, W4, b4, nullptr, Zf, nullptr, N);

    // --- normalize + project ---
    final_kernel<<<(N * 64 + 255) / 256, 256, 0, stream>>>(Zf, Wm, bm, out, N);
}

// Round 6
// 958.186 us; speedup vs baseline: 4.9084x; 1.1409x over previous
//
#include <hip/hip_runtime.h>
#include <hip/hip_fp16.h>
#include <math.h>

#define HDIM 128

typedef _Float16 f16x8 __attribute__((ext_vector_type(8)));
typedef float f32x4 __attribute__((ext_vector_type(4)));

struct alignas(8) half4 { __half2 lo, hi; };

__device__ __forceinline__ float4 h4_to_f4(half4 h) {
    float2 a = __half22float2(h.lo), b = __half22float2(h.hi);
    return make_float4(a.x, a.y, b.x, b.y);
}
__device__ __forceinline__ half4 f4_to_h4(float4 f) {
    half4 h;
    h.lo = __float22half2_rn(make_float2(f.x, f.y));
    h.hi = __float22half2_rn(make_float2(f.z, f.w));
    return h;
}

// ---------------- degree / CSR build ----------------

__global__ void degs_kernel(const int* __restrict__ src, const int* __restrict__ dst,
                            int* __restrict__ degS, int* __restrict__ degD, int E) {
    int e = blockIdx.x * blockDim.x + threadIdx.x;
    if (e < E) {
        atomicAdd(&degS[src[e]], 1);
        atomicAdd(&degD[dst[e]], 1);
    }
}

__global__ void dinv_kernel(const int* __restrict__ degS, float* __restrict__ dinv, int N) {
    int i = blockIdx.x * blockDim.x + threadIdx.x;
    if (i < N) { int d = degS[i]; dinv[i] = d > 0 ? rsqrtf((float)d) : 0.f; }
}

// single-block exclusive scan of degD -> rp[0..N], rp[N] = E
__global__ __launch_bounds__(1024)
void scan_kernel(const int* __restrict__ deg, int* __restrict__ rp, int N) {
    __shared__ int part[1024];
    int tid = threadIdx.x;
    int chunk = (N + 1023) / 1024;
    int start = tid * chunk;
    int end = start + chunk; if (end > N) end = N;
    int s = 0;
    for (int i = start; i < end; ++i) s += deg[i];
    part[tid] = s;
    __syncthreads();
    for (int off = 1; off < 1024; off <<= 1) {
        int v = (tid >= off) ? part[tid - off] : 0;
        __syncthreads();
        part[tid] += v;
        __syncthreads();
    }
    int run = (tid == 0) ? 0 : part[tid - 1];
    for (int i = start; i < end; ++i) { rp[i] = run; run += deg[i]; }
    if (start < N && end == N) rp[N] = run;
}

__global__ void scatter_kernel(const int* __restrict__ src, const int* __restrict__ dst,
                               const float* __restrict__ dinv, const int* __restrict__ rp,
                               int* __restrict__ cursor, int2* __restrict__ ev, int E) {
    int e = blockIdx.x * blockDim.x + threadIdx.x;
    if (e >= E) return;
    int s = src[e], d = dst[e];
    float w = -dinv[s] * dinv[d];
    int pos = atomicAdd(&cursor[d], 1);
    ev[rp[d] + pos] = make_int2(s, __float_as_int(w));
}

// ---------------- pull propagation (fp16 tables, fp32 accumulate) ----------
template <int GBN, int PBN>
__global__ __launch_bounds__(256)
void pull128(const __half* __restrict__ t, const int* __restrict__ rp,
             const int2* __restrict__ ev, const __half* __restrict__ prev,
             const float* __restrict__ bnp, __half* __restrict__ outp,
             float alpha, int N) {
    int node = blockIdx.x * 4 + (threadIdx.x >> 6);
    if (node >= N) return;
    int lane = threadIdx.x & 63;
    int c4 = (lane & 31) * 4;     // channel group (4 channels, 8 B fp16)
    int epar = lane >> 5;         // edge parity for this half-wave

    float4 sc = make_float4(1.f, 1.f, 1.f, 1.f);
    float4 sh = make_float4(0.f, 0.f, 0.f, 0.f);
    if (GBN || PBN) {
        sc = *(const float4*)(bnp + c4);
        sh = *(const float4*)(bnp + 128 + c4);
    }

    int b = rp[node], e = rp[node + 1];
    float4 a0 = {0,0,0,0}, a1 = {0,0,0,0}, a2 = {0,0,0,0}, a3 = {0,0,0,0};

    int j = b;
    for (; j + 8 <= e; j += 8) {
        int2 s0 = ev[j + 0 + epar];
        int2 s1 = ev[j + 2 + epar];
        int2 s2 = ev[j + 4 + epar];
        int2 s3 = ev[j + 6 + epar];
        float4 r0 = h4_to_f4(*(const half4*)(t + (size_t)s0.x * HDIM + c4));
        float4 r1 = h4_to_f4(*(const half4*)(t + (size_t)s1.x * HDIM + c4));
        float4 r2 = h4_to_f4(*(const half4*)(t + (size_t)s2.x * HDIM + c4));
        float4 r3 = h4_to_f4(*(const half4*)(t + (size_t)s3.x * HDIM + c4));
        float w0 = __int_as_float(s0.y), w1 = __int_as_float(s1.y);
        float w2 = __int_as_float(s2.y), w3 = __int_as_float(s3.y);
        if (GBN) {
            r0.x = r0.x * sc.x + sh.x; r0.y = r0.y * sc.y + sh.y; r0.z = r0.z * sc.z + sh.z; r0.w = r0.w * sc.w + sh.w;
            r1.x = r1.x * sc.x + sh.x; r1.y = r1.y * sc.y + sh.y; r1.z = r1.z * sc.z + sh.z; r1.w = r1.w * sc.w + sh.w;
            r2.x = r2.x * sc.x + sh.x; r2.y = r2.y * sc.y + sh.y; r2.z = r2.z * sc.z + sh.z; r2.w = r2.w * sc.w + sh.w;
            r3.x = r3.x * sc.x + sh.x; r3.y = r3.y * sc.y + sh.y; r3.z = r3.z * sc.z + sh.z; r3.w = r3.w * sc.w + sh.w;
        }
        a0.x += w0 * r0.x; a0.y += w0 * r0.y; a0.z += w0 * r0.z; a0.w += w0 * r0.w;
        a1.x += w1 * r1.x; a1.y += w1 * r1.y; a1.z += w1 * r1.z; a1.w += w1 * r1.w;
        a2.x += w2 * r2.x; a2.y += w2 * r2.y; a2.z += w2 * r2.z; a2.w += w2 * r2.w;
        a3.x += w3 * r3.x; a3.y += w3 * r3.y; a3.z += w3 * r3.z; a3.w += w3 * r3.w;
    }
    for (; j + 2 <= e; j += 2) {
        int2 s0 = ev[j + epar];
        float w0 = __int_as_float(s0.y);
        float4 r0 = h4_to_f4(*(const half4*)(t + (size_t)s0.x * HDIM + c4));
        if (GBN) {
            r0.x = r0.x * sc.x + sh.x; r0.y = r0.y * sc.y + sh.y; r0.z = r0.z * sc.z + sh.z; r0.w = r0.w * sc.w + sh.w;
        }
        a0.x += w0 * r0.x; a0.y += w0 * r0.y; a0.z += w0 * r0.z; a0.w += w0 * r0.w;
    }
    if (j < e && epar == 0) {
        int2 s0 = ev[j];
        float w0 = __int_as_float(s0.y);
        float4 r0 = h4_to_f4(*(const half4*)(t + (size_t)s0.x * HDIM + c4));
        if (GBN) {
            r0.x = r0.x * sc.x + sh.x; r0.y = r0.y * sc.y + sh.y; r0.z = r0.z * sc.z + sh.z; r0.w = r0.w * sc.w + sh.w;
        }
        a1.x += w0 * r0.x; a1.y += w0 * r0.y; a1.z += w0 * r0.z; a1.w += w0 * r0.w;
    }

    float4 s4;
    s4.x = (a0.x + a1.x) + (a2.x + a3.x);
    s4.y = (a0.y + a1.y) + (a2.y + a3.y);
    s4.z = (a0.z + a1.z) + (a2.z + a3.z);
    s4.w = (a0.w + a1.w) + (a2.w + a3.w);
    s4.x += __shfl_xor(s4.x, 32);
    s4.y += __shfl_xor(s4.y, 32);
    s4.z += __shfl_xor(s4.z, 32);
    s4.w += __shfl_xor(s4.w, 32);

    if (lane < 32) {
        size_t o = (size_t)node * HDIM + c4;
        float4 r;
        r.x = alpha * s4.x; r.y = alpha * s4.y; r.z = alpha * s4.z; r.w = alpha * s4.w;
        if (!GBN) {
            float4 pv = h4_to_f4(*(const half4*)(prev + o));
            if (PBN) {
                pv.x = pv.x * sc.x + sh.x; pv.y = pv.y * sc.y + sh.y;
                pv.z = pv.z * sc.z + sh.z; pv.w = pv.w * sc.w + sh.w;
            }
            r.x -= pv.x; r.y -= pv.y; r.z -= pv.z; r.w -= pv.w;
        }
        *(half4*)(outp + o) = f4_to_h4(r);
    }
}

__global__ void pull3(const float* __restrict__ t, const float* __restrict__ prev,
                      const int* __restrict__ rp, const int2* __restrict__ ev,
                      float* __restrict__ outp, float alpha, int N) {
    int node = blockIdx.x * blockDim.x + threadIdx.x;
    if (node >= N) return;
    int b = rp[node], e = rp[node + 1];
    float a0 = 0.f, a1 = 0.f, a2 = 0.f;
    for (int j = b; j < e; ++j) {
        int2 sw = ev[j];
        float w = __int_as_float(sw.y);
        const float* r = t + (size_t)sw.x * 3;
        a0 += w * r[0]; a1 += w * r[1]; a2 += w * r[2];
    }
    float r0 = alpha * a0, r1 = alpha * a1, r2 = alpha * a2;
    if (prev) {
        r0 -= prev[node * 3 + 0];
        r1 -= prev[node * 3 + 1];
        r2 -= prev[node * 3 + 2];
    }
    outp[node * 3 + 0] = r0;
    outp[node * 3 + 1] = r1;
    outp[node * 3 + 2] = r2;
}

// ---------------- weight prep: fold BN(T0) into W, transpose, fp16 --------
// Wt[n*512 + sel*128 + k] = fp16( W[sel][k][n] * (sel==0 ? bnp_scale[k] : 1) )
__global__ void wprep_kernel(const float* __restrict__ W, const float* __restrict__ bnp,
                             _Float16* __restrict__ Wt) {
    int idx = blockIdx.x * 256 + threadIdx.x;   // 65536
    int n = idx >> 9, sk = idx & 511;
    int sel = sk >> 7, k = sk & 127;
    float v = W[sel * 16384 + k * 128 + n];
    if (sel == 0) v *= bnp[k];
    Wt[idx] = (_Float16)v;
}

// bias2[n] = b[n] + sum_k bnp_shift[k] * W[0][k][n]
__global__ void bias2_kernel(const float* __restrict__ W, const float* __restrict__ bnp,
                             const float* __restrict__ b, float* __restrict__ bias2) {
    int n = threadIdx.x;
    float s = b[n];
    for (int k = 0; k < 128; ++k) s += bnp[128 + k] * W[k * 128 + n];
    bias2[n] = s;
}

// ---------------- MFMA Cheb GEMM -------------------------------------------
// Z = T0@Wt0 + T1@Wt1 + T2@Wt2 + T3@Wt3 + bias2  (BN of T0 pre-folded into Wt/bias2)
// block = 64 rows x 128 cols, 4 waves 2x2 (wave = 32 rows x 64 cols).
// A frags straight from global fp16 tables; B (Wt, 128 KB) L2-resident; no LDS tiles.
template <int ACT, int STATS, int OUTH>
__global__ __launch_bounds__(256)
void gemm_mfma(const __half* __restrict__ T0, const __half* __restrict__ T1,
               const __half* __restrict__ T2, const __half* __restrict__ T3,
               const _Float16* __restrict__ Wt, const float* __restrict__ bias2,
               __half* __restrict__ outh, float* __restrict__ outf,
               float* __restrict__ stats, int N) {
    __shared__ float s_sum[128];
    __shared__ float s_sq[128];
    int tid = threadIdx.x;
    if (STATS) {
        if (tid < 128) { s_sum[tid] = 0.f; s_sq[tid] = 0.f; }
        __syncthreads();
    }
    int wave = tid >> 6, lane = tid & 63;
    int wr = wave >> 1, wc = wave & 1;
    int m = lane & 15, quad = lane >> 4;
    int row0 = blockIdx.x * 64 + wr * 32;

    size_t ra0 = (size_t)(min(row0 + m, N - 1)) * HDIM;
    size_t ra1 = (size_t)(min(row0 + 16 + m, N - 1)) * HDIM;

    const __half* Ts[4] = {T0, T1, T2, T3};
    f32x4 acc[2][4];
#pragma unroll
    for (int rt = 0; rt < 2; ++rt)
#pragma unroll
        for (int ct = 0; ct < 4; ++ct) acc[rt][ct] = (f32x4){0.f, 0.f, 0.f, 0.f};

    const _Float16* Wn = Wt + (size_t)(wc * 64 + m) * 512;   // row n = wc*64+ct*16+m

    for (int sel = 0; sel < 4; ++sel) {
        const _Float16* Tp = (const _Float16*)Ts[sel];
#pragma unroll
        for (int kt = 0; kt < 4; ++kt) {
            int ko = kt * 32 + quad * 8;
            f16x8 a0 = *(const f16x8*)(Tp + ra0 + ko);
            f16x8 a1 = *(const f16x8*)(Tp + ra1 + ko);
            const _Float16* Wb = Wn + sel * 128 + ko;
#pragma unroll
            for (int ct = 0; ct < 4; ++ct) {
                f16x8 bf = *(const f16x8*)(Wb + (size_t)ct * 16 * 512);
                acc[0][ct] = __builtin_amdgcn_mfma_f32_16x16x32_f16(a0, bf, acc[0][ct], 0, 0, 0);
                acc[1][ct] = __builtin_amdgcn_mfma_f32_16x16x32_f16(a1, bf, acc[1][ct], 0, 0, 0);
            }
        }
    }

    // epilogue: D tile (rt,ct): row = row0 + rt*16 + quad*4 + r, col = wc*64 + ct*16 + m
    float csum[4] = {}, csq[4] = {};
#pragma unroll
    for (int ct = 0; ct < 4; ++ct) {
        int col = wc * 64 + ct * 16 + m;
        float bv = bias2[col];
#pragma unroll
        for (int rt = 0; rt < 2; ++rt) {
#pragma unroll
            for (int r = 0; r < 4; ++r) {
                int drow = row0 + rt * 16 + quad * 4 + r;
                if (drow < N) {
                    float v = acc[rt][ct][r] + bv;
                    if (ACT == 1) v = v >= 0.f ? v : 0.01f * v;
                    else if (ACT == 2) v = fmaxf(v, 0.f);
                    if (OUTH) outh[(size_t)drow * HDIM + col] = __float2half(v);
                    else      outf[(size_t)drow * HDIM + col] = v;
                    if (STATS) { csum[ct] += v; csq[ct] += v * v; }
                }
            }
        }
    }
    if (STATS) {
#pragma unroll
        for (int ct = 0; ct < 4; ++ct) {
            int col = wc * 64 + ct * 16 + m;
            atomicAdd(&s_sum[col], csum[ct]);
            atomicAdd(&s_sq[col], csq[ct]);
        }
        __syncthreads();
        if (tid < 128) {
            atomicAdd(&stats[tid], s_sum[tid]);
            atomicAdd(&stats[128 + tid], s_sq[tid]);
        }
    }
}

// ---------------- layer-1 (input dim 3) fused GEMM, grid-stride ----------------
__global__ __launch_bounds__(256)
void gemm1_kernel(const float* __restrict__ x, const float* __restrict__ t1,
                  const float* __restrict__ t2, const float* __restrict__ t3,
                  const float* __restrict__ W1, const float* __restrict__ b1,
                  __half* __restrict__ out, float* __restrict__ stats, int N) {
    __shared__ float s_sum[128];
    __shared__ float s_sq[128];
    int tid = threadIdx.x;
    int c = tid & 127;
    if (tid < 128) { s_sum[tid] = 0.f; s_sq[tid] = 0.f; }
    __syncthreads();
    float wreg[12];
#pragma unroll
    for (int i = 0; i < 12; ++i) wreg[i] = W1[i * 128 + c];
    float bias = b1[c];
    const float* Ts[4] = {x, t1, t2, t3};
    float lsum = 0.f, lsq = 0.f;
    for (int row = blockIdx.x * 2 + (tid >> 7); row < N; row += gridDim.x * 2) {
        float v = bias;
#pragma unroll
        for (int k = 0; k < 4; ++k) {
            const float* t = Ts[k];
#pragma unroll
            for (int d = 0; d < 3; ++d)
                v += t[row * 3 + d] * wreg[k * 3 + d];
        }
        v = v >= 0.f ? v : 0.01f * v;   // leaky_relu
        out[(size_t)row * HDIM + c] = __float2half(v);
        lsum += v; lsq += v * v;
    }
    atomicAdd(&s_sum[c], lsum);
    atomicAdd(&s_sq[c], lsq);
    __syncthreads();
    if (tid < 128) {
        atomicAdd(&stats[tid], s_sum[tid]);
        atomicAdd(&stats[128 + tid], s_sq[tid]);
    }
}

// ---------------- BN finalize: stats -> (scale, shift) ----------------
__global__ void bnfin_kernel(const float* __restrict__ stats, const float* __restrict__ g,
                             const float* __restrict__ be, float* __restrict__ bnp, float invN) {
    int c = threadIdx.x;  // 128 threads
    float m = stats[c] * invN;
    float v = stats[128 + c] * invN - m * m;
    float sc = g[c] * rsqrtf(v + 1e-5f);
    bnp[c] = sc;
    bnp[128 + c] = be[c] - m * sc;
}

// ---------------- final: L2-normalize row + project to 3 ----------------
__global__ void final_kernel(const float* __restrict__ Z, const float* __restrict__ Wm,
                             const float* __restrict__ bm, float* __restrict__ out, int N) {
    int gid = blockIdx.x * blockDim.x + threadIdx.x;
    int node = gid >> 6;
    int lane = threadIdx.x & 63;
    if (node >= N) return;
    const float* z = Z + (size_t)node * HDIM;
    float z0 = z[lane], z1 = z[lane + 64];
    float sq = z0 * z0 + z1 * z1;
    float d0 = z0 * Wm[lane * 3 + 0] + z1 * Wm[(lane + 64) * 3 + 0];
    float d1 = z0 * Wm[lane * 3 + 1] + z1 * Wm[(lane + 64) * 3 + 1];
    float d2 = z0 * Wm[lane * 3 + 2] + z1 * Wm[(lane + 64) * 3 + 2];
#pragma unroll
    for (int off = 32; off > 0; off >>= 1) {
        sq += __shfl_down(sq, off);
        d0 += __shfl_down(d0, off);
        d1 += __shfl_down(d1, off);
        d2 += __shfl_down(d2, off);
    }
    if (lane == 0) {
        float inv = 1.f / fmaxf(sqrtf(sq), 1e-12f);
        out[node * 3 + 0] = d0 * inv + bm[0];
        out[node * 3 + 1] = d1 * inv + bm[1];
        out[node * 3 + 2] = d2 * inv + bm[2];
    }
}

// ---------------- host ----------------

extern "C" void kernel_launch(void* const* d_in, const int* in_sizes, int n_in,
                              void* d_out, int out_size, void* d_ws, size_t ws_size,
                              hipStream_t stream) {
    const float* x  = (const float*)d_in[0];
    const int*   ei = (const int*)d_in[1];
    const float* W1 = (const float*)d_in[2];
    const float* b1 = (const float*)d_in[3];
    const float* W2 = (const float*)d_in[4];
    const float* b2 = (const float*)d_in[5];
    const float* W3 = (const float*)d_in[6];
    const float* b3 = (const float*)d_in[7];
    const float* W4 = (const float*)d_in[8];
    const float* b4 = (const float*)d_in[9];
    const float* g1 = (const float*)d_in[10];
    const float* be1 = (const float*)d_in[11];
    const float* g2 = (const float*)d_in[12];
    const float* be2 = (const float*)d_in[13];
    const float* g3 = (const float*)d_in[14];
    const float* be3 = (const float*)d_in[15];
    const float* Wm = (const float*)d_in[16];
    const float* bm = (const float*)d_in[17];
    float* out = (float*)d_out;

    const int N = in_sizes[0] / 3;
    const int E = in_sizes[1] / 2;
    const size_t NH = (size_t)N * HDIM;
    const int* src = ei;
    const int* dst = ei + E;

    // ---- workspace layout ----
    char* base = (char*)d_ws;
    int* degS   = (int*)base;            base += (size_t)N * 4;
    int* degD   = (int*)base;            base += (size_t)N * 4;
    int* cursor = (int*)base;            base += (size_t)N * 4;
    int* rp     = (int*)base;            base += (size_t)(N + 2) * 4;
    int2* ev    = (int2*)base;           base += (size_t)E * 8;
    float* dinv = (float*)base;          base += (size_t)N * 4;
    __half* Za  = (__half*)base;         base += NH * 2;
    __half* Zb  = (__half*)base;         base += NH * 2;
    __half* T1  = (__half*)base;         base += NH * 2;
    __half* T2  = (__half*)base;         base += NH * 2;
    __half* T3  = (__half*)base;         base += NH * 2;
    float* Zf   = (float*)base;          base += NH * 4;   // layer-4 out, fp32
    float* x1   = (float*)base;          base += (size_t)N * 3 * 4;
    float* x2   = (float*)base;          base += (size_t)N * 3 * 4;
    float* x3   = (float*)base;          base += (size_t)N * 3 * 4;
    float* stats = (float*)base;         base += 256 * 4;
    float* bnp1  = (float*)base;         base += 256 * 4;
    float* bnp2  = (float*)base;         base += 256 * 4;
    float* bnp3  = (float*)base;         base += 256 * 4;
    _Float16* Wt = (_Float16*)base;      base += (size_t)65536 * 2;  // 4x128x128 fp16 transposed
    float* bias2 = (float*)base;         base += 128 * 4;

    const int EB = (E + 255) / 256;
    const int NB = (N + 255) / 256;
    const int GB = (N + 63) / 64;         // mfma gemm row tiles (64 rows)
    const int PB = (N + 3) / 4;           // pull128 blocks (4 nodes/block)
    const float invN = 1.f / (float)N;

    // --- CSR build + edge weights ---
    hipMemsetAsync(degS, 0, (size_t)N * 3 * 4, stream);   // degS, degD, cursor
    degs_kernel<<<EB, 256, 0, stream>>>(src, dst, degS, degD, E);
    dinv_kernel<<<NB, 256, 0, stream>>>(degS, dinv, N);
    scan_kernel<<<1, 1024, 0, stream>>>(degD, rp, N);
    scatter_kernel<<<EB, 256, 0, stream>>>(src, dst, dinv, rp, cursor, ev, E);

    // --- layer 1 (dim 3) -> Za (fp16), bnp1 ---
    pull3<<<NB, 256, 0, stream>>>(x,  nullptr, rp, ev, x1, 1.f, N);
    pull3<<<NB, 256, 0, stream>>>(x1, x,       rp, ev, x2, 2.f, N);
    pull3<<<NB, 256, 0, stream>>>(x2, x1,      rp, ev, x3, 2.f, N);
    hipMemsetAsync(stats, 0, 256 * 4, stream);
    gemm1_kernel<<<512, 256, 0, stream>>>(x, x1, x2, x3, W1, b1, Za, stats, N);
    bnfin_kernel<<<1, 128, 0, stream>>>(stats, g1, be1, bnp1, invN);

    // --- layer 2 (leaky + BN): input BN(Za,bnp1) -> Zb, bnp2 ---
    wprep_kernel<<<256, 256, 0, stream>>>(W2, bnp1, Wt);
    bias2_kernel<<<1, 128, 0, stream>>>(W2, bnp1, b2, bias2);
    pull128<1, 0><<<PB, 256, 0, stream>>>(Za, rp, ev, nullptr, bnp1, T1, 1.f, N);
    pull128<0, 1><<<PB, 256, 0, stream>>>(T1, rp, ev, Za, bnp1, T2, 2.f, N);
    pull128<0, 0><<<PB, 256, 0, stream>>>(T2, rp, ev, T1, nullptr, T3, 2.f, N);
    hipMemsetAsync(stats, 0, 256 * 4, stream);
    gemm_mfma<1, 1, 1><<<GB, 256, 0, stream>>>(Za, T1, T2, T3, Wt, bias2, Zb, nullptr, stats, N);
    bnfin_kernel<<<1, 128, 0, stream>>>(stats, g2, be2, bnp2, invN);

    // --- layer 3 (relu + BN): input BN(Zb,bnp2) -> Za, bnp3 ---
    wprep_kernel<<<256, 256, 0, stream>>>(W3, bnp2, Wt);
    bias2_kernel<<<1, 128, 0, stream>>>(W3, bnp2, b3, bias2);
    pull128<1, 0><<<PB, 256, 0, stream>>>(Zb, rp, ev, nullptr, bnp2, T1, 1.f, N);
    pull128<0, 1><<<PB, 256, 0, stream>>>(T1, rp, ev, Zb, bnp2, T2, 2.f, N);
    pull128<0, 0><<<PB, 256, 0, stream>>>(T2, rp, ev, T1, nullptr, T3, 2.f, N);
    hipMemsetAsync(stats, 0, 256 * 4, stream);
    gemm_mfma<2, 1, 1><<<GB, 256, 0, stream>>>(Zb, T1, T2, T3, Wt, bias2, Za, nullptr, stats, N);
    bnfin_kernel<<<1, 128, 0, stream>>>(stats, g3, be3, bnp3, invN);

    // --- layer 4 (no act/BN): input BN(Za,bnp3) -> Zf (fp32) ---
    wprep_kernel<<<256, 256, 0, stream>>>(W4, bnp3, Wt);
    bias2_kernel<<<1, 128, 0, stream>>>(W4, bnp3, b4, bias2);
    pull128<1, 0><<<PB, 256, 0, stream>>>(Za, rp, ev, nullptr, bnp3, T1, 1.f, N);
    pull128<0, 1><<<PB, 256, 0, stream>>>(T1, rp, ev, Za, bnp3, T2, 2.f, N);
    pull128<0, 0><<<PB, 256, 0, stream>>>(T2, rp, ev, T1, nullptr, T3, 2.f, N);
    gemm_mfma<0, 0, 0><<<GB, 256, 0, stream>>>(Za, T1, T2, T3, Wt, bias2, nullptr, Zf, nullptr, N);

    // --- normalize + project ---
    final_kernel<<<(N * 64 + 255) / 256, 256, 0, stream>>>(Zf, Wm, bm, out, N);
}